// Round 10
// baseline (516.528 us; speedup 1.0000x reference)
//
#include <hip/hip_runtime.h>
#include <hip/hip_bf16.h>
#include <math.h>

#define BB 2
#define TT 1024
#define BT (BB*TT)          // 2048 rows
#define DM 1024
#define DI 2048
#define DS 128
#define NHS 32              // ssm heads
#define PDIM 64             // ssm headdim
#define NHA 16              // attn heads
#define HD 64
#define FFN_ 4096
#define NZX 4384            // 2*DI + 2*DS + NHS
#define NXBC 2304           // DI + 2*DS
#define NXBCD 2336          // xBC (2304) + dt (32) raw gemm-out width
#define CL 128              // scan chunk length
#define NC 8                // chunks

typedef __hip_bfloat16 bf16;
typedef short bf16x8 __attribute__((ext_vector_type(8)));
typedef float f32x4 __attribute__((ext_vector_type(4)));

__device__ __forceinline__ float b2f(bf16 v){ return __bfloat162float(v); }
__device__ __forceinline__ bf16 f2b(float v){ return __float2bfloat16(v); }

// async global->LDS, 16B per lane; LDS dest = wave-uniform base + lane*16
__device__ __forceinline__ void gload16(const void* g, void* l) {
  __builtin_amdgcn_global_load_lds(
      (const __attribute__((address_space(1))) unsigned int*)g,
      (__attribute__((address_space(3))) unsigned int*)l,
      16, 0, 0);
}

// ---------------- RMSNorm: write fp32 X copy + bf16 normalized H -------------
__global__ void k_rms_in(const float* __restrict__ xin, float* __restrict__ X,
                         bf16* __restrict__ H) {
  int row = blockIdx.x;
  int tid = threadIdx.x;          // 256 threads, 4 elems each (DM=1024)
  const float* xr = xin + (size_t)row * DM;
  float v[4]; float ss = 0.f;
  #pragma unroll
  for (int i = 0; i < 4; ++i) { v[i] = xr[tid*4+i]; ss += v[i]*v[i]; }
  __shared__ float red[256];
  red[tid] = ss; __syncthreads();
  for (int s = 128; s > 0; s >>= 1) { if (tid < s) red[tid] += red[tid+s]; __syncthreads(); }
  float scale = rsqrtf(red[0]/(float)DM + 1e-6f);
  float* Xr = X + (size_t)row*DM; bf16* Hr = H + (size_t)row*DM;
  #pragma unroll
  for (int i = 0; i < 4; ++i) { Xr[tid*4+i] = v[i]; Hr[tid*4+i] = f2b(v[i]*scale); }
}

// ---------------- fused: X += sum(4 partials); H = bf16(rmsnorm(X)) ----------
// Race-free: each block touches only its own row.
__global__ void k_reduce4_rms(const float* __restrict__ p0, const float* __restrict__ p1,
                              const float* __restrict__ p2, const float* __restrict__ p3,
                              float* __restrict__ X, bf16* __restrict__ H) {
  int row = blockIdx.x; int tid = threadIdx.x;
  size_t base = (size_t)row*DM + tid*4;
  float4 a = *(const float4*)(p0 + base);
  float4 b = *(const float4*)(p1 + base);
  float4 c = *(const float4*)(p2 + base);
  float4 d = *(const float4*)(p3 + base);
  float4 x = *(const float4*)(X + base);
  float v[4];
  v[0] = x.x + a.x + b.x + c.x + d.x;
  v[1] = x.y + a.y + b.y + c.y + d.y;
  v[2] = x.z + a.z + b.z + c.z + d.z;
  v[3] = x.w + a.w + b.w + c.w + d.w;
  float ss = v[0]*v[0] + v[1]*v[1] + v[2]*v[2] + v[3]*v[3];
  __shared__ float red[256];
  red[tid] = ss; __syncthreads();
  for (int s = 128; s > 0; s >>= 1) { if (tid < s) red[tid] += red[tid+s]; __syncthreads(); }
  float scale = rsqrtf(red[0]/(float)DM + 1e-6f);
  float4 res; res.x = v[0]; res.y = v[1]; res.z = v[2]; res.w = v[3];
  *(float4*)(X + base) = res;
  bf16* Hr = H + (size_t)row*DM + tid*4;
  #pragma unroll
  for (int i = 0; i < 4; ++i) Hr[i] = f2b(v[i]*scale);
}

// ---------------- fused rmsnorm + token-shift: X -> XK, XR -------------------
// READ-ONLY on X (the preceding reduce kernel finished writing X) -> race-free.
__global__ void k_rms_shift(const float* __restrict__ X, const float* __restrict__ maak,
                            const float* __restrict__ maar,
                            bf16* __restrict__ XK, bf16* __restrict__ XR) {
  int row = blockIdx.x; int t = row & (TT - 1);
  int tid = threadIdx.x;
  const float* xr = X + (size_t)row*DM;
  const float* xp = xr - DM;
  float v[4], pv[4]; float ss = 0.f, ssp = 0.f;
  #pragma unroll
  for (int i = 0; i < 4; ++i) {
    int c = tid*4 + i;
    v[i] = xr[c]; ss += v[i]*v[i];
    pv[i] = (t > 0) ? xp[c] : 0.f; ssp += pv[i]*pv[i];
  }
  __shared__ float red[256], red2[256];
  red[tid] = ss; red2[tid] = ssp; __syncthreads();
  for (int s = 128; s > 0; s >>= 1) {
    if (tid < s) { red[tid] += red[tid+s]; red2[tid] += red2[tid+s]; }
    __syncthreads();
  }
  float scale  = rsqrtf(red[0]/(float)DM + 1e-6f);
  float scalep = (t > 0) ? rsqrtf(red2[0]/(float)DM + 1e-6f) : 0.f;
  bf16* xk = XK + (size_t)row*DM; bf16* xrw = XR + (size_t)row*DM;
  #pragma unroll
  for (int i = 0; i < 4; ++i) {
    int c = tid*4 + i;
    float h = v[i]*scale;
    float xx = pv[i]*scalep - h;
    xk[c]  = f2b(h + xx*maak[c]);
    xrw[c] = f2b(h + xx*maar[c]);
  }
}

// ---------------- weight cast + transpose: Wt[n][k] = bf16(W[k][n]) ----------
__global__ void k_tcast(const float* __restrict__ W, bf16* __restrict__ Wt,
                        int K, int N) {
  __shared__ float t[32][33];
  int tx = threadIdx.x, ty = threadIdx.y;
  int n0 = blockIdx.x*32, k0 = blockIdx.y*32;
  #pragma unroll
  for (int i = 0; i < 4; ++i) {
    int k = k0 + ty + i*8, n = n0 + tx;
    t[ty + i*8][tx] = (n < N) ? W[(size_t)k*N + n] : 0.f;
  }
  __syncthreads();
  #pragma unroll
  for (int i = 0; i < 4; ++i) {
    int n = n0 + ty + i*8, k = k0 + tx;
    Wt[(size_t)n*K + k] = f2b(t[tx][ty + i*8]);
  }
}

// ---------------- MFMA GEMM 128x128, BK=64, 2-phase pipelined, 8 waves -------
// BK=64 halves barrier count vs BK=32 and doubles MFMA-per-barrier (16/wave).
// LDS 64 KB (2buf x 2op x 128x64 bf16) -> 2 blocks/CU at 512 thr. Wave w
// stages 16 rows x 128 B per operand: 2 gload16 (8-row slabs), lane -> row
// (l>>3), col (l&7)*8; wave-uniform LDS base + lane*16 contract kept.
template<int EPI, bool ADD, bool OUTBF>
__global__ __launch_bounds__(512)
void mfma_gemm(const bf16* __restrict__ A, const bf16* __restrict__ Bt,
               float* __restrict__ C, bf16* __restrict__ Cbf,
               int M, int N, int K) {
  __shared__ bf16 As[2][128*64];
  __shared__ bf16 Bs[2][128*64];
  int tid = threadIdx.x;
  int wave = tid >> 6, lane = tid & 63;
  int m_l = lane & 15, quad = lane >> 4;
  int wr = (wave & 1) * 64, wc = (wave >> 1) * 32;
  int row0 = blockIdx.y * 128, col0 = blockIdx.x * 128;
  f32x4 acc[4][2];
  #pragma unroll
  for (int i = 0; i < 4; ++i)
    #pragma unroll
    for (int j = 0; j < 2; ++j) acc[i][j] = (f32x4){0.f,0.f,0.f,0.f};
  int lr8 = lane >> 3;           // 0..7 row within 8-row slab
  int lc8 = (lane & 7) * 8;      // 0..56
  int rbase = 16*wave;
  // prologue: stage K-tile 0
  #pragma unroll
  for (int g = 0; g < 2; ++g) {
    int rb = rbase + 8*g;
    gload16(&A [(size_t)(row0 + rb + lr8)*K + lc8], &As[0][rb*64]);
    gload16(&Bt[(size_t)(col0 + rb + lr8)*K + lc8], &Bs[0][rb*64]);
  }
  __syncthreads();
  int nit = K >> 6;
  int cur = 0;
  for (int it = 0; it < nit; ++it) {
    if (it + 1 < nit) {
      int kn = (it + 1) << 6;
      #pragma unroll
      for (int g = 0; g < 2; ++g) {
        int rb = rbase + 8*g;
        gload16(&A [(size_t)(row0 + rb + lr8)*K + kn + lc8], &As[cur^1][rb*64]);
        gload16(&Bt[(size_t)(col0 + rb + lr8)*K + kn + lc8], &Bs[cur^1][rb*64]);
      }
    }
    bf16x8 af[4][2], bfv[2][2];
    #pragma unroll
    for (int i = 0; i < 4; ++i)
      #pragma unroll
      for (int kf = 0; kf < 2; ++kf)
        af[i][kf] = *(const bf16x8*)&As[cur][(wr + i*16 + m_l)*64 + kf*32 + quad*8];
    #pragma unroll
    for (int j = 0; j < 2; ++j)
      #pragma unroll
      for (int kf = 0; kf < 2; ++kf)
        bfv[j][kf] = *(const bf16x8*)&Bs[cur][(wc + j*16 + m_l)*64 + kf*32 + quad*8];
    #pragma unroll
    for (int kf = 0; kf < 2; ++kf)
      #pragma unroll
      for (int i = 0; i < 4; ++i)
        #pragma unroll
        for (int j = 0; j < 2; ++j)
          acc[i][j] = __builtin_amdgcn_mfma_f32_16x16x32_bf16(af[i][kf], bfv[j][kf], acc[i][j], 0, 0, 0);
    __syncthreads();   // drains the prefetch (implicit vmcnt(0)) + syncs
    cur ^= 1;
  }
  #pragma unroll
  for (int i = 0; i < 4; ++i) {
    #pragma unroll
    for (int j = 0; j < 2; ++j) {
      int col = col0 + wc + j*16 + m_l;
      if (col < N) {
        #pragma unroll
        for (int r = 0; r < 4; ++r) {
          int row = row0 + wr + i*16 + quad*4 + r;
          float v = acc[i][j][r];
          if (EPI == 1) { v = fmaxf(v, 0.f); v = v*v; }          // relu^2
          else if (EPI == 2) v = 1.f/(1.f + __expf(-v));          // sigmoid
          if (OUTBF)      Cbf[(size_t)row*N + col] = f2b(v);
          else if (ADD)   C[(size_t)row*N + col] += v;
          else            C[(size_t)row*N + col]  = v;
        }
      }
    }
  }
}

// ---------------- split-K GEMM, BK=64, 2-phase pipelined, 8 waves ------------
__global__ __launch_bounds__(512)
void mfma_sk32(const bf16* __restrict__ A, const bf16* __restrict__ Bt,
               float* __restrict__ P0, float* __restrict__ P1,
               float* __restrict__ P2, float* __restrict__ P3,
               int M, int N, int K, int kchunk) {
  __shared__ bf16 As[2][128*64];
  __shared__ bf16 Bs[2][128*64];
  int tid = threadIdx.x;
  int wave = tid >> 6, lane = tid & 63;
  int m_l = lane & 15, quad = lane >> 4;
  int wr = (wave & 1) * 64, wc = (wave >> 1) * 32;
  int row0 = blockIdx.y * 128, col0 = blockIdx.x * 128;
  int kbeg = blockIdx.z * kchunk;
  f32x4 acc[4][2];
  #pragma unroll
  for (int i = 0; i < 4; ++i)
    #pragma unroll
    for (int j = 0; j < 2; ++j) acc[i][j] = (f32x4){0.f,0.f,0.f,0.f};
  int lr8 = lane >> 3;           // 0..7
  int lc8 = (lane & 7) * 8;      // 0..56
  int rbase = 16*wave;
  // prologue: stage K-tile kbeg
  #pragma unroll
  for (int g = 0; g < 2; ++g) {
    int rb = rbase + 8*g;
    gload16(&A [(size_t)(row0 + rb + lr8)*K + kbeg + lc8], &As[0][rb*64]);
    gload16(&Bt[(size_t)(col0 + rb + lr8)*K + kbeg + lc8], &Bs[0][rb*64]);
  }
  __syncthreads();
  int nit = kchunk >> 6;
  int cur = 0;
  for (int it = 0; it < nit; ++it) {
    if (it + 1 < nit) {
      int kn = kbeg + ((it + 1) << 6);
      #pragma unroll
      for (int g = 0; g < 2; ++g) {
        int rb = rbase + 8*g;
        gload16(&A [(size_t)(row0 + rb + lr8)*K + kn + lc8], &As[cur^1][rb*64]);
        gload16(&Bt[(size_t)(col0 + rb + lr8)*K + kn + lc8], &Bs[cur^1][rb*64]);
      }
    }
    bf16x8 af[4][2], bfv[2][2];
    #pragma unroll
    for (int i = 0; i < 4; ++i)
      #pragma unroll
      for (int kf = 0; kf < 2; ++kf)
        af[i][kf] = *(const bf16x8*)&As[cur][(wr + i*16 + m_l)*64 + kf*32 + quad*8];
    #pragma unroll
    for (int j = 0; j < 2; ++j)
      #pragma unroll
      for (int kf = 0; kf < 2; ++kf)
        bfv[j][kf] = *(const bf16x8*)&Bs[cur][(wc + j*16 + m_l)*64 + kf*32 + quad*8];
    #pragma unroll
    for (int kf = 0; kf < 2; ++kf)
      #pragma unroll
      for (int i = 0; i < 4; ++i)
        #pragma unroll
        for (int j = 0; j < 2; ++j)
          acc[i][j] = __builtin_amdgcn_mfma_f32_16x16x32_bf16(af[i][kf], bfv[j][kf], acc[i][j], 0, 0, 0);
    __syncthreads();
    cur ^= 1;
  }
  float* P = (blockIdx.z == 0) ? P0 : (blockIdx.z == 1) ? P1 : (blockIdx.z == 2) ? P2 : P3;
  #pragma unroll
  for (int i = 0; i < 4; ++i) {
    #pragma unroll
    for (int j = 0; j < 2; ++j) {
      int col = col0 + wc + j*16 + m_l;
      if (col < N) {
        #pragma unroll
        for (int r = 0; r < 4; ++r) {
          int row = row0 + wr + i*16 + quad*4 + r;
          P[(size_t)row*N + col] = acc[i][j][r];
        }
      }
    }
  }
}

// ---------------- split-K reduce: dst (+)= epi(sum of Z partials) ------------
template<int Z, int EPI, bool ADD>
__global__ void k_reduce(float* __restrict__ dst, const float* __restrict__ p0,
                         const float* __restrict__ p1, const float* __restrict__ p2,
                         const float* __restrict__ p3) {
  size_t i = ((size_t)blockIdx.x*256 + threadIdx.x)*4;
  float4 a = *(const float4*)(p0 + i);
  float4 b = *(const float4*)(p1 + i);
  float r0 = a.x + b.x, r1 = a.y + b.y, r2 = a.z + b.z, r3 = a.w + b.w;
  if (Z == 4) {
    float4 c = *(const float4*)(p2 + i);
    float4 d = *(const float4*)(p3 + i);
    r0 += c.x + d.x; r1 += c.y + d.y; r2 += c.z + d.z; r3 += c.w + d.w;
  }
  if (EPI == 2) {
    r0 = 1.f/(1.f + __expf(-r0)); r1 = 1.f/(1.f + __expf(-r1));
    r2 = 1.f/(1.f + __expf(-r2)); r3 = 1.f/(1.f + __expf(-r3));
  }
  if (ADD) {
    float4 o = *(const float4*)(dst + i);
    r0 += o.x; r1 += o.y; r2 += o.z; r3 += o.w;
  }
  float4 res; res.x = r0; res.y = r1; res.z = r2; res.w = r3;
  *(float4*)(dst + i) = res;
}

// -------- fused: out = X + sigmoid(r0+r1) * (k0+k1+k2+k3) --------------------
__global__ void k_reduce_final6(const float* __restrict__ k0, const float* __restrict__ k1,
                                const float* __restrict__ k2, const float* __restrict__ k3,
                                const float* __restrict__ r0p, const float* __restrict__ r1p,
                                const float* __restrict__ X, float* __restrict__ out) {
  size_t i = ((size_t)blockIdx.x*256 + threadIdx.x)*4;
  float4 a = *(const float4*)(k0 + i);
  float4 b = *(const float4*)(k1 + i);
  float4 c = *(const float4*)(k2 + i);
  float4 d = *(const float4*)(k3 + i);
  float4 ra = *(const float4*)(r0p + i);
  float4 rb = *(const float4*)(r1p + i);
  float4 x = *(const float4*)(X + i);
  float kvx = a.x + b.x + c.x + d.x, kvy = a.y + b.y + c.y + d.y;
  float kvz = a.z + b.z + c.z + d.z, kvw = a.w + b.w + c.w + d.w;
  float sx = 1.f/(1.f + __expf(-(ra.x + rb.x)));
  float sy = 1.f/(1.f + __expf(-(ra.y + rb.y)));
  float sz = 1.f/(1.f + __expf(-(ra.z + rb.z)));
  float sw = 1.f/(1.f + __expf(-(ra.w + rb.w)));
  float4 res;
  res.x = x.x + sx*kvx; res.y = x.y + sy*kvy;
  res.z = x.z + sz*kvz; res.w = x.w + sw*kvw;
  *(float4*)(out + i) = res;
}

// ---------------- SSM conv (K=4) + silu + dt softplus; bf16 xBC out ----------
__global__ void k_conv_ssm(const float* __restrict__ ZXr, const float* __restrict__ cw,
                           const float* __restrict__ cb, const float* __restrict__ dtb,
                           bf16* __restrict__ XBCb, float* __restrict__ DT) {
  int bt = blockIdx.x; int b = bt >> 10; int t = bt & 1023;
  int tid = threadIdx.x;
  for (int c = tid; c < NXBC; c += 256) {
    float acc = cb[c];
    #pragma unroll
    for (int kk = 0; kk < 4; ++kk) {
      int ts = t - 3 + kk;
      if (ts >= 0) acc += cw[c*4+kk] * ZXr[((size_t)(b*TT+ts))*NXBCD + c];
    }
    float s = acc / (1.f + __expf(-acc));  // silu
    XBCb[(size_t)bt*NXBC + c] = f2b(s);
  }
  if (tid < NHS) {
    float x = ZXr[(size_t)bt*NXBCD + NXBC + tid] + dtb[tid];
    float sp = (x > 20.f) ? x : log1pf(__expf(x));
    DT[(size_t)bt*NHS + tid] = sp;
  }
}

// ---------------- scan pass 1: intra-chunk via MFMA, 8 waves -----------------
__global__ __launch_bounds__(512)
void k_scan1(const bf16* __restrict__ xbcb, const float* __restrict__ dt,
             const float* __restrict__ A_log, const float* __restrict__ Dmv,
             float* __restrict__ Y, float* __restrict__ SC, float* __restrict__ CUM) {
  int bc = blockIdx.x;
  int bh = bc >> 3, c = bc & 7;
  int b = bh >> 5, h = bh & 31;
  int tid = threadIdx.x, wave = tid >> 6, lane = tid & 63;
  int col = lane & 15, quad = lane >> 4;
  int t0 = c * CL;
  __shared__ bf16 sB[128*136];   // B rows [s][n]; later BwT [n][s]
  __shared__ bf16 sC[128*136];   // C rows [t][n]; later Ps [t][s]
  __shared__ bf16 sxT[64*136];   // x^T [p][t]
  __shared__ float sL[128], sdt[128], sW[128];
  float A = -__expf(A_log[h]);
  float Dmh = Dmv[h];
  for (int e = tid; e < 128*16; e += 512) {
    int r = e >> 4, ch = e & 15;
    const bf16* row = xbcb + (size_t)(b*TT + t0 + r)*NXBC;
    *(uint4*)&sB[r*136 + ch*8] = *(const uint4*)&row[2048 + ch*8];
    *(uint4*)&sC[r*136 + ch*8] = *(const uint4*)&row[2176 + ch*8];
  }
  for (int e = tid; e < 64*128; e += 512) {
    int p = e & 63, t = e >> 6;
    sxT[p*136 + t] = xbcb[(size_t)(b*TT + t0 + t)*NXBC + h*64 + p];
  }
  if (tid < 128) sdt[tid] = dt[(size_t)(b*TT + t0 + tid)*NHS + h];
  __syncthreads();
  if (wave == 0) {
    float a0 = sdt[2*lane]*A, a1 = sdt[2*lane+1]*A;
    float tot = a0 + a1;
    #pragma unroll
    for (int off = 1; off < 64; off <<= 1) {
      float up = __shfl_up(tot, off);
      if (lane >= off) tot += up;
    }
    sL[2*lane+1] = tot;
    sL[2*lane]   = tot - a1;
  }
  __syncthreads();
  // MFMA1: g[t][s] = C @ B^T; wave tiling 2 (t-halves) x 4 (s-quarters)
  int wr = (wave & 1)*64, wc = (wave >> 1)*32;
  f32x4 g[4][2];
  #pragma unroll
  for (int i = 0; i < 4; ++i)
    #pragma unroll
    for (int j = 0; j < 2; ++j) g[i][j] = (f32x4){0.f,0.f,0.f,0.f};
  #pragma unroll
  for (int kf = 0; kf < 4; ++kf) {
    bf16x8 af[4], bfr[2];
    #pragma unroll
    for (int i = 0; i < 4; ++i) af[i]  = *(const bf16x8*)&sC[(wr + i*16 + col)*136 + kf*32 + quad*8];
    #pragma unroll
    for (int j = 0; j < 2; ++j) bfr[j] = *(const bf16x8*)&sB[(wc + j*16 + col)*136 + kf*32 + quad*8];
    #pragma unroll
    for (int i = 0; i < 4; ++i)
      #pragma unroll
      for (int j = 0; j < 2; ++j)
        g[i][j] = __builtin_amdgcn_mfma_f32_16x16x32_bf16(af[i], bfr[j], g[i][j], 0, 0, 0);
  }
  float Lend = sL[127];
  if (tid < 128) sW[tid] = __expf(Lend - sL[tid]) * sdt[tid];
  __syncthreads();
  if (tid < 128) CUM[(size_t)bh*TT + t0 + tid] = __expf(sL[tid]);
  #pragma unroll
  for (int i = 0; i < 4; ++i) {
    #pragma unroll
    for (int j = 0; j < 2; ++j) {
      int sl = wc + j*16 + col;
      #pragma unroll
      for (int r = 0; r < 4; ++r) {
        int tl = wr + i*16 + quad*4 + r;
        float v = (sl <= tl) ? g[i][j][r] * __expf(sL[tl] - sL[sl]) * sdt[sl] : 0.f;
        sC[tl*136 + sl] = f2b(v);
      }
    }
  }
  for (int e = tid; e < 128*128; e += 512) {
    int n = e & 127, s = e >> 7;
    sB[n*136 + s] = f2b(b2f(xbcb[(size_t)(b*TT + t0 + s)*NXBC + 2048 + n]) * sW[s]);
  }
  __syncthreads();
  // MFMA2: y[t][p] = Ps @ x^T^T; wave tiling 4 (t-quarters) x 2 (p-halves)
  int tb = (wave & 3)*32, pb = (wave >> 2)*32;
  f32x4 ya[2][2];
  #pragma unroll
  for (int i2 = 0; i2 < 2; ++i2)
    #pragma unroll
    for (int jd = 0; jd < 2; ++jd) ya[i2][jd] = (f32x4){0.f,0.f,0.f,0.f};
  #pragma unroll
  for (int kf = 0; kf < 4; ++kf) {
    bf16x8 pa[2], xa[2];
    #pragma unroll
    for (int i2 = 0; i2 < 2; ++i2)
      pa[i2] = *(const bf16x8*)&sC[(tb + i2*16 + col)*136 + kf*32 + quad*8];
    #pragma unroll
    for (int jd = 0; jd < 2; ++jd)
      xa[jd] = *(const bf16x8*)&sxT[(pb + jd*16 + col)*136 + kf*32 + quad*8];
    #pragma unroll
    for (int i2 = 0; i2 < 2; ++i2)
      #pragma unroll
      for (int jd = 0; jd < 2; ++jd)
        ya[i2][jd] = __builtin_amdgcn_mfma_f32_16x16x32_bf16(pa[i2], xa[jd], ya[i2][jd], 0, 0, 0);
  }
  #pragma unroll
  for (int i2 = 0; i2 < 2; ++i2) {
    #pragma unroll
    for (int jd = 0; jd < 2; ++jd) {
      int p = pb + jd*16 + col;
      #pragma unroll
      for (int r = 0; r < 4; ++r) {
        int tl = tb + i2*16 + quad*4 + r;
        float xv = b2f(sxT[p*136 + tl]);
        Y[(size_t)(b*TT + t0 + tl)*DI + h*64 + p] = ya[i2][jd][r] + xv*Dmh;
      }
    }
  }
  // MFMA3: SC[p][n] = x^T @ Bw^T; wave tiling 4 (p-16-blocks) x 2 (n-halves)
  int pb3 = (wave & 3)*16, nb = (wave >> 2)*64;
  f32x4 sa[4];
  #pragma unroll
  for (int nt = 0; nt < 4; ++nt) sa[nt] = (f32x4){0.f,0.f,0.f,0.f};
  #pragma unroll
  for (int kf = 0; kf < 4; ++kf) {
    bf16x8 xpa = *(const bf16x8*)&sxT[(pb3 + col)*136 + kf*32 + quad*8];
    #pragma unroll
    for (int nt = 0; nt < 4; ++nt) {
      bf16x8 bwa = *(const bf16x8*)&sB[(nb + nt*16 + col)*136 + kf*32 + quad*8];
      sa[nt] = __builtin_amdgcn_mfma_f32_16x16x32_bf16(xpa, bwa, sa[nt], 0, 0, 0);
    }
  }
  #pragma unroll
  for (int nt = 0; nt < 4; ++nt) {
    int n = nb + nt*16 + col;
    #pragma unroll
    for (int r = 0; r < 4; ++r) {
      int p = pb3 + quad*4 + r;
      SC[((size_t)(bh*NC + c)*64 + p)*128 + n] = sa[nt][r];
    }
  }
}

// ---------------- scan pass 2: sequential inter-chunk combine (fp32) ---------
__global__ __launch_bounds__(512)
void k_scan2(float* __restrict__ SC, const float* __restrict__ CUM) {
  int bh = blockIdx.x;
  int tid = threadIdx.x;
  int p = tid >> 3, g = tid & 7;
  float S[16];
  #pragma unroll
  for (int j = 0; j < 16; ++j) S[j] = 0.f;
  for (int c = 0; c < NC; ++c) {
    size_t base = ((size_t)(bh*NC + c)*64 + p)*128 + g*16;
    float Ptot = CUM[(size_t)bh*TT + c*CL + (CL-1)];
    float tmp[16];
    #pragma unroll
    for (int j = 0; j < 16; ++j) tmp[j] = SC[base + j];
    #pragma unroll
    for (int j = 0; j < 16; ++j) SC[base + j] = S[j];
    #pragma unroll
    for (int j = 0; j < 16; ++j) S[j] = S[j]*Ptot + tmp[j];
  }
}

// ---------------- scan pass 3: Y += CUM[t] * (C @ S_init^T) via MFMA ---------
__global__ __launch_bounds__(256)
void k_scan3(const bf16* __restrict__ xbcb, const float* __restrict__ SC,
             const float* __restrict__ CUM, float* __restrict__ Y) {
  int bc = blockIdx.x;
  int bh = bc >> 3, c = bc & 7;
  if (c == 0) return;
  int b = bh >> 5, h = bh & 31;
  int tid = threadIdx.x, wave = tid >> 6, lane = tid & 63;
  int col = lane & 15, quad = lane >> 4;
  int t0 = c * CL;
  __shared__ bf16 sCt[128*136];
  __shared__ bf16 sS[64*136];
  __shared__ float sCum[128];
  for (int e = tid; e < 128*16; e += 256) {
    int r = e >> 4, ch = e & 15;
    *(uint4*)&sCt[r*136 + ch*8] =
      *(const uint4*)&xbcb[(size_t)(b*TT + t0 + r)*NXBC + 2176 + ch*8];
  }
  for (int e = tid; e < 64*128; e += 256) {
    int n = e & 127, p = e >> 7;
    sS[p*136 + n] = f2b(SC[((size_t)(bh*NC + c)*64 + p)*128 + n]);
  }
  if (tid < 128) sCum[tid] = CUM[(size_t)bh*TT + t0 + tid];
  __syncthreads();
  f32x4 ya[2][4];
  #pragma unroll
  for (int i2 = 0; i2 < 2; ++i2)
    #pragma unroll
    for (int jd = 0; jd < 4; ++jd) ya[i2][jd] = (f32x4){0.f,0.f,0.f,0.f};
  #pragma unroll
  for (int kf = 0; kf < 4; ++kf) {
    bf16x8 pa[2], sv[4];
    #pragma unroll
    for (int i2 = 0; i2 < 2; ++i2)
      pa[i2] = *(const bf16x8*)&sCt[(wave*32 + i2*16 + col)*136 + kf*32 + quad*8];
    #pragma unroll
    for (int jd = 0; jd < 4; ++jd)
      sv[jd] = *(const bf16x8*)&sS[(jd*16 + col)*136 + kf*32 + quad*8];
    #pragma unroll
    for (int i2 = 0; i2 < 2; ++i2)
      #pragma unroll
      for (int jd = 0; jd < 4; ++jd)
        ya[i2][jd] = __builtin_amdgcn_mfma_f32_16x16x32_bf16(pa[i2], sv[jd], ya[i2][jd], 0, 0, 0);
  }
  #pragma unroll
  for (int i2 = 0; i2 < 2; ++i2) {
    #pragma unroll
    for (int jd = 0; jd < 4; ++jd) {
      int p = jd*16 + col;
      #pragma unroll
      for (int r = 0; r < 4; ++r) {
        int tl = wave*32 + i2*16 + quad*4 + r;
        Y[(size_t)(b*TT + t0 + tl)*DI + h*64 + p] += sCum[tl]*ya[i2][jd][r];
      }
    }
  }
}

// ---------------- gate: Ybf = bf16(rmsnorm(y * silu(z)) * mnorm_w) -----------
__global__ void k_gate(const float* __restrict__ Y, const float* __restrict__ Z,
                       const float* __restrict__ mnw, bf16* __restrict__ Ybf) {
  int row = blockIdx.x; int tid = threadIdx.x;
  const float* yr = Y + (size_t)row*DI;
  const float* zr = Z + (size_t)row*DI;
  float gv[8]; float ss = 0.f;
  #pragma unroll
  for (int i = 0; i < 8; ++i) {
    int c = tid*8 + i;
    float z = zr[c];
    float sz = z / (1.f + __expf(-z));
    float v = yr[c]*sz;
    gv[i] = v; ss += v*v;
  }
  __shared__ float red[256];
  red[tid] = ss; __syncthreads();
  for (int s = 128; s > 0; s >>= 1) { if (tid < s) red[tid] += red[tid+s]; __syncthreads(); }
  float scale = rsqrtf(red[0]/(float)DI + 1e-5f);
  bf16* br = Ybf + (size_t)row*DI;
  #pragma unroll
  for (int i = 0; i < 8; ++i) { int c = tid*8 + i; br[c] = f2b(gv[i]*scale*mnw[c]); }
}

// ------ q/k/v causal dwconv (K=3) with FUSED split-K reduce of QKV -----------
__global__ void k_conv_qkv(const float* __restrict__ P0, const float* __restrict__ P1,
                           const float* qw, const float* qb, const float* kw, const float* kb,
                           const float* vw, const float* vb,
                           bf16* __restrict__ Qb, bf16* __restrict__ Kb, bf16* __restrict__ Vtb) {
  int bt = blockIdx.x; int b = bt >> 10; int t = bt & 1023;
  int tid = threadIdx.x;
  for (int c = tid; c < 1152; c += 256) {
    if (c < 1024) {
      int h = c >> 6, d = c & 63;
      float acc = qb[d];
      #pragma unroll
      for (int kk = 0; kk < 3; ++kk) {
        int ts = t-2+kk;
        if (ts >= 0) { size_t ix = ((size_t)(b*TT+ts))*1152 + c; acc += qw[d*3+kk] * (P0[ix] + P1[ix]); }
      }
      Qb[((size_t)(b*NHA + h)*TT + t)*HD + d] = f2b(acc * 0.125f);  // 1/sqrt(64)
    } else if (c < 1088) {
      int d = c - 1024;
      float acc = kb[d];
      #pragma unroll
      for (int kk = 0; kk < 3; ++kk) {
        int ts = t-2+kk;
        if (ts >= 0) { size_t ix = ((size_t)(b*TT+ts))*1152 + c; acc += kw[d*3+kk] * (P0[ix] + P1[ix]); }
      }
      Kb[(size_t)bt*HD + d] = f2b(acc);
    } else {
      int d = c - 1088;
      float acc = vb[d];
      #pragma unroll
      for (int kk = 0; kk < 3; ++kk) {
        int ts = t-2+kk;
        if (ts >= 0) { size_t ix = ((size_t)(b*TT+ts))*1152 + c; acc += vw[d*3+kk] * (P0[ix] + P1[ix]); }
      }
      Vtb[((size_t)(b*HD + d))*TT + t] = f2b(acc);
    }
  }
}

// ---------------- split-KV MFMA flash attention, max-free, 8 waves -----------
__global__ __launch_bounds__(512)
void k_flash_sk(const bf16* __restrict__ Qb, const bf16* __restrict__ Kb,
                const bf16* __restrict__ Vtb, float* __restrict__ Op,
                float* __restrict__ Lp) {
  int qt = blockIdx.x >> 1, z = blockIdx.x & 1;
  int h = blockIdx.y, b = blockIdx.z;
  int n = qt + 1;
  int kmid = (n + 1) >> 1;
  int kbeg = z ? kmid : 0;
  int kend = z ? n : kmid;
  int tid = threadIdx.x, wave = tid >> 6, lane = tid & 63;
  int col = lane & 15, quad = lane >> 4;
  int t0 = qt * 128;
  __shared__ bf16 Ks[128*72];
  __shared__ bf16 Vs[64*136];
  __shared__ bf16 Ps[8][16*136];
  const bf16* Qbase = Qb + ((size_t)(b*NHA + h))*TT*HD;
  float lst[4];
  f32x4 oacc[4];
  #pragma unroll
  for (int r = 0; r < 4; ++r) lst[r] = 0.f;
  #pragma unroll
  for (int jd = 0; jd < 4; ++jd) oacc[jd] = (f32x4){0.f,0.f,0.f,0.f};
  if (kbeg < kend) {
    bf16x8 qf[2];
    #pragma unroll
    for (int kf = 0; kf < 2; ++kf)
      qf[kf] = *(const bf16x8*)&Qbase[(size_t)(t0 + wave*16 + col)*HD + kf*32 + quad*8];

    for (int kt = kbeg; kt < kend; ++kt) {
      int s0 = kt * 128;
      __syncthreads();
      for (int e = tid; e < 1024; e += 512) {
        int r = e >> 3, ch = e & 7;
        *(uint4*)&Ks[r*72 + ch*8] = *(const uint4*)&Kb[((size_t)(b*TT + s0 + r))*HD + ch*8];
      }
      for (int e = tid; e < 1024; e += 512) {
        int d = e >> 4, ch = e & 15;
        *(uint4*)&Vs[d*136 + ch*8] = *(const uint4*)&Vtb[((size_t)(b*HD + d))*TT + s0 + ch*8];
      }
      __syncthreads();
      f32x4 sacc[8];
      #pragma unroll
      for (int j = 0; j < 8; ++j) sacc[j] = (f32x4){0.f,0.f,0.f,0.f};
      __builtin_amdgcn_s_setprio(1);
      #pragma unroll
      for (int j = 0; j < 8; ++j) {
        bf16x8 kf0 = *(const bf16x8*)&Ks[(j*16 + col)*72 + quad*8];
        bf16x8 kf1 = *(const bf16x8*)&Ks[(j*16 + col)*72 + 32 + quad*8];
        sacc[j] = __builtin_amdgcn_mfma_f32_16x16x32_bf16(qf[0], kf0, sacc[j], 0, 0, 0);
        sacc[j] = __builtin_amdgcn_mfma_f32_16x16x32_bf16(qf[1], kf1, sacc[j], 0, 0, 0);
      }
      __builtin_amdgcn_s_setprio(0);
      bool diag = (kt == qt);
      #pragma unroll
      for (int r = 0; r < 4; ++r) {
        int rowloc = wave*16 + quad*4 + r;
        #pragma unroll
        for (int j = 0; j < 8; ++j) {
          float pv = __expf(sacc[j][r]);
          if (diag && (j*16 + col > rowloc)) pv = 0.f;
          sacc[j][r] = pv;
          lst[r] += pv;
        }
      }
      #pragma unroll
      for (int j = 0; j < 8; ++j)
        #pragma unroll
        for (int r = 0; r < 4; ++r)
          Ps[wave][(quad*4 + r)*136 + j*16 + col] = f2b(sacc[j][r]);
      __builtin_amdgcn_s_setprio(1);
      bf16x8 pa[4];
      #pragma unroll
      for (int kf = 0; kf < 4; ++kf)
        pa[kf] = *(const bf16x8*)&Ps[wave][col*136 + kf*32 + quad*8];
      #pragma unroll
      for (int jd = 0; jd < 4; ++jd) {
        #pragma unroll
        for (int kf = 0; kf < 4; ++kf) {
          bf16x8 vbf = *(const bf16x8*)&Vs[(jd*16 + col)*136 + kf*32 + quad*8];
          oacc[jd] = __builtin_amdgcn_mfma_f32_16x16x32_bf16(pa[kf], vbf, oacc[jd], 0, 0, 0);
        }
      }
      __builtin_amdgcn_s_setprio(0);
    }
    #pragma unroll
    for (int r = 0; r < 4; ++r) {
      float l = lst[r];
      l += __shfl_xor(l, 1);
      l += __shfl_xor(l, 2);
      l += __shfl_xor(l, 4);
      l += __shfl_xor(l, 8);
      lst[r] = l;
    }
  }
  if (qt == 0 && z == 1) return;
  size_t robase = ((size_t)((z*BB + b)*NHA + h))*TT + t0;
  #pragma unroll
  for (int jd = 0; jd < 4; ++jd) {
    int d = jd*16 + col;
    #pragma unroll
    for (int r = 0; r < 4; ++r) {
      int tl = wave*16 + quad*4 + r;
      Op[(robase + tl)*HD + d] = oacc[jd][r];
    }
  }
  if (col == 0) {
    #pragma unroll
    for (int r = 0; r < 4; ++r) {
      int tl = wave*16 + quad*4 + r;
      Lp[robase + tl] = lst[r];
    }
  }
}

// ---------------- attention split-KV combine (max-free: pure sums) -----------
__global__ void k_att_comb(const float* __restrict__ Op, const float* __restrict__ Lp,
                           bf16* __restrict__ outb) {
  int idx = blockIdx.x*256 + threadIdx.x;   // one thread = 4 consecutive d
  int e = idx*4;
  int c = e & (DM - 1); int h = c >> 6; int d = c & 63;
  int bt = e >> 10; int t = bt & (TT - 1); int b = bt >> 10;
  int qt = t >> 7;
  size_t r0 = ((size_t)(b*NHA + h))*TT + t;
  float4 o0 = *(const float4*)&Op[r0*HD + d];
  float l = Lp[r0];
  float ox = o0.x, oy = o0.y, oz = o0.z, ow = o0.w;
  if (qt > 0) {
    size_t r1 = ((size_t)((BB + b)*NHA + h))*TT + t;
    float4 o1 = *(const float4*)&Op[r1*HD + d];
    l += Lp[r1];
    ox += o1.x; oy += o1.y; oz += o1.z; ow += o1.w;
  }
  float inv = 1.f / l;
  bf16* p = outb + (size_t)bt*DM + c;
  p[0] = f2b(ox*inv); p[1] = f2b(oy*inv); p[2] = f2b(oz*inv); p[3] = f2b(ow*inv);
}

// =============================================================================
extern "C" void kernel_launch(void* const* d_in, const int* in_sizes, int n_in,
                              void* d_out, int out_size, void* d_ws, size_t ws_size,
                              hipStream_t stream) {
  const float* x_in    = (const float*)d_in[0];
  const float* W_in    = (const float*)d_in[1];
  const float* conv_w  = (const float*)d_in[2];
  const float* conv_b  = (const float*)d_in[3];
  const float* A_log   = (const float*)d_in[4];
  const float* Dm      = (const float*)d_in[5];
  const float* dt_bias = (const float*)d_in[6];
  const float* mnorm_w = (const float*)d_in[7];
  const float* W_out   = (const float*)d_in[8];
  const float* W_qkv   = (const float*)d_in[9];
  const float* W_cproj = (const float*)d_in[10];
  const float* qconv_w = (const float*)d_in[11];
  const float* qconv_b = (const float*)d_in[12];
  const float* kconv_w = (const float*)d_in[13];
  const float* kconv_b = (const float*)d_in[14];
  const float* vconv_w = (const float*)d_in[15];
  const float* vconv_b = (const float*)d_in[16];
  const float* maa_k   = (const float*)d_in[17];
  const float* maa_r   = (const float*)d_in[18];
  const float* W_key   = (const float*)d_in[19];
  const float* W_rec   = (const float*)d_in[20];
  const float* W_val   = (const float*)d_in[21];
  float* out = (float*)d_out;

  float* ws = (float*)d_ws;
  float* X       = ws;                       // [0, 2,097,152)
  bf16*  Hbf     = (bf16*)(ws + 2097152);    // 2,097,152 bf16
  float* Zbuf    = ws + 3145728;             // [3,145,728, 7,340,032)
  float* XBCDraw = ws + 7340032;             // [7,340,032, 12,124,160)
  float* XBC     = ws + 12124160;            // [12,124,160, 16,842,752)
  float* DT      = ws + 16842752;            // +65,536
  float* CUM     = ws + 16908288;            // +65,536
  float* Y       = ws + 16973824;            // [16,973,824, 21,168,128)

  bf16*  Wt_in    = (bf16*)XBC;
  bf16*  XBCb     = (bf16*)XBC;
  float* SC       = XBCDraw;
  bf16*  Ybf      = (bf16*)XBC;
  bf16*  Wt_out   = (bf16*)(XBC + 2097152);
  bf16*  Wt_qkv   = (bf16*)XBC;
  bf16*  Qb       = (bf16*)XBCDraw;
  bf16*  Kb       = (bf16*)(XBCDraw + 1048576);
  bf16*  Vtb      = (bf16*)(XBCDraw + 1114112);
  bf16*  ATTNbf   = (bf16*)Y;
  bf16*  Wt_cproj = (bf16*)(Y + 1048576);
  bf16*  XKbf     = (bf16*)XBC;
  bf16*  XRbf     = (bf16*)(XBC + 1048576);
  bf16*  Wt_key   = (bf16*)Zbuf;
  bf16*  KFbf     = (bf16*)XBCDraw;
  bf16*  Wt_val   = (bf16*)Zbuf;
  bf16*  Wt_rec   = (bf16*)Zbuf;
  // flash split-KV partials (live only between k_conv_qkv and k_att_comb):
  float* FOp      = Zbuf;                    // 2 x 2,097,152 fp32
  float* FLp      = ws + 2097152;            // 65,536 (Hbf region, dead here)

  dim3 thr256(256), thr512(512);
  dim3 tblk(32, 8);

  // 1. X = x; Hbf = rmsnorm(x)
  k_rms_in<<<BT, thr256, 0, stream>>>(x_in, X, Hbf);
  // 2. [Z | XBCDraw] = Hbf @ W_in  (wide, full-K)
  k_tcast<<<dim3(4480/32, 1024/32), tblk, 0, stream>>>(W_in, Wt_in, 1024, NZX);
  mfma_gemm<0,false,false><<<dim3(16, 16), thr512, 0, stream>>>(Hbf, Wt_in, Zbuf, nullptr, BT, 2048, 1024);
  mfma_gemm<0,false,false><<<dim3(19, 16), thr512, 0, stream>>>(Hbf, Wt_in + (size_t)2048*1024, XBCDraw, nullptr, BT, NXBCD, 1024);
  // 3. conv+silu on xBC (bf16 out), softplus dt
  k_conv_ssm<<<BT, thr256, 0, stream>>>(XBCDraw, conv_w, conv_b, dt_bias, XBCb, DT);
  // 4. SSM chunked scan via MFMA (scan1 8 waves)
  k_scan1<<<BB*NHS*NC, thr512, 0, stream>>>(XBCb, DT, A_log, Dm, Y, SC, CUM);
  k_scan2<<<BB*NHS, thr512, 0, stream>>>(SC, CUM);
  k_scan3<<<BB*NHS*NC, thr256, 0, stream>>>(XBCb, SC, CUM, Y);
  // 5. gate + mnorm -> Ybf
  k_gate<<<BT, thr256, 0, stream>>>(Y, Zbuf, mnorm_w, Ybf);
  // 6+7. X += Ybf @ W_out (split-K z=4) -> fused reduce + rmsnorm -> Hbf
  k_tcast<<<dim3(1024/32, 2048/32), tblk, 0, stream>>>(W_out, Wt_out, 2048, 1024);
  mfma_sk32<<<dim3(8, 16, 4), thr512, 0, stream>>>(Ybf, Wt_out,
      Zbuf, Zbuf + 2097152, XBCDraw, XBCDraw + 2097152, BT, 1024, 2048, 512);
  k_reduce4_rms<<<BT, thr256, 0, stream>>>(Zbuf, Zbuf + 2097152, XBCDraw, XBCDraw + 2097152, X, Hbf);
  // 8. QKV partials = Hbf @ W_qkv (split-K z=2; p0 -> Zbuf, p1 -> Y;
  //    reduce FUSED into conv_qkv)
  k_tcast<<<dim3(1152/32, 1024/32), tblk, 0, stream>>>(W_qkv, Wt_qkv, 1024, 1152);
  mfma_sk32<<<dim3(9, 16, 2), thr512, 0, stream>>>(Hbf, Wt_qkv,
      Zbuf, Y, Zbuf, Zbuf, BT, 1152, 1024, 512);
  // 9. q/k/v convs (fused QKV reduce) -> bf16 Qb (scaled), Kb, Vtb (transposed)
  k_conv_qkv<<<BT, thr256, 0, stream>>>(Zbuf, Y, qconv_w, qconv_b, kconv_w, kconv_b, vconv_w, vconv_b, Qb, Kb, Vtb);
  // 10. split-KV max-free flash attention (8 waves) -> partials -> combine
  k_flash_sk<<<dim3((TT/128)*2, NHA, BB), thr512, 0, stream>>>(Qb, Kb, Vtb, FOp, FLp);
  k_att_comb<<<(BT*DM)/(256*4), thr256, 0, stream>>>(FOp, FLp, ATTNbf);
  // 11. X += ATTNbf @ W_cproj (split-K z=2, partials in Zbuf); separate reduce
  k_tcast<<<dim3(1024/32, 1024/32), tblk, 0, stream>>>(W_cproj, Wt_cproj, 1024, 1024);
  mfma_sk32<<<dim3(8, 16, 2), thr512, 0, stream>>>(ATTNbf, Wt_cproj,
      Zbuf, Zbuf + 2097152, Zbuf, Zbuf, BT, 1024, 1024, 512);
  k_reduce<2,0,true><<<2048, thr256, 0, stream>>>(X, Zbuf, Zbuf + 2097152, Zbuf, Zbuf);
  // 12+13. fused rmsnorm + token shift (READ-ONLY on X) -> XKbf, XRbf
  k_rms_shift<<<BT, thr256, 0, stream>>>(X, maa_k, maa_r, XKbf, XRbf);
  // 14. KFbf = bf16(relu(XKbf @ W_key)^2)  (wide, full-K, 512 blocks)
  k_tcast<<<dim3(4096/32, 1024/32), tblk, 0, stream>>>(W_key, Wt_key, 1024, 4096);
  mfma_gemm<1,false,true><<<dim3(32, 16), thr512, 0, stream>>>(XKbf, Wt_key, nullptr, KFbf, BT, 4096, 1024);
  // 15. KV partials = KFbf @ W_val  (split-K z=4; NO reduce -- fused into final)
  k_tcast<<<dim3(1024/32, 4096/32), tblk, 0, stream>>>(W_val, Wt_val, 4096, 1024);
  mfma_sk32<<<dim3(8, 16, 4), thr512, 0, stream>>>(KFbf, Wt_val,
      Y, Y + 2097152, XBC + 2621440, Zbuf + 2097152, BT, 1024, 4096, 1024);
  // 16. R partials = XRbf @ W_rec (split-K z=2 -> XBCDraw; KFbf dead)
  k_tcast<<<dim3(1024/32, 1024/32), tblk, 0, stream>>>(W_rec, Wt_rec, 1024, 1024);
  mfma_sk32<<<dim3(8, 16, 2), thr512, 0, stream>>>(XRbf, Wt_rec,
      XBCDraw, XBCDraw + 2097152, XBCDraw, XBCDraw, BT, 1024, 1024, 512);
  // 17. fused: out = X + sigmoid(r0+r1) * (k0+k1+k2+k3)
  k_reduce_final6<<<2048, thr256, 0, stream>>>(
      Y, Y + 2097152, XBC + 2621440, Zbuf + 2097152,
      XBCDraw, XBCDraw + 2097152, X, out);
}

// Round 11
// 496.170 us; speedup vs baseline: 1.0410x; 1.0410x over previous
//
#include <hip/hip_runtime.h>
#include <hip/hip_bf16.h>
#include <math.h>

#define BB 2
#define TT 1024
#define BT (BB*TT)          // 2048 rows
#define DM 1024
#define DI 2048
#define DS 128
#define NHS 32              // ssm heads
#define PDIM 64             // ssm headdim
#define NHA 16              // attn heads
#define HD 64
#define FFN_ 4096
#define NZX 4384            // 2*DI + 2*DS + NHS
#define NXBC 2304           // DI + 2*DS
#define NXBCD 2336          // xBC (2304) + dt (32) raw gemm-out width
#define CL 128              // scan chunk length
#define NC 8                // chunks

typedef __hip_bfloat16 bf16;
typedef short bf16x8 __attribute__((ext_vector_type(8)));
typedef float f32x4 __attribute__((ext_vector_type(4)));

__device__ __forceinline__ float b2f(bf16 v){ return __bfloat162float(v); }
__device__ __forceinline__ bf16 f2b(float v){ return __float2bfloat16(v); }

// async global->LDS, 16B per lane; LDS dest = wave-uniform base + lane*16
__device__ __forceinline__ void gload16(const void* g, void* l) {
  __builtin_amdgcn_global_load_lds(
      (const __attribute__((address_space(1))) unsigned int*)g,
      (__attribute__((address_space(3))) unsigned int*)l,
      16, 0, 0);
}

// ---------------- RMSNorm: write fp32 X copy + bf16 normalized H -------------
__global__ void k_rms_in(const float* __restrict__ xin, float* __restrict__ X,
                         bf16* __restrict__ H) {
  int row = blockIdx.x;
  int tid = threadIdx.x;          // 256 threads, 4 elems each (DM=1024)
  const float* xr = xin + (size_t)row * DM;
  float v[4]; float ss = 0.f;
  #pragma unroll
  for (int i = 0; i < 4; ++i) { v[i] = xr[tid*4+i]; ss += v[i]*v[i]; }
  __shared__ float red[256];
  red[tid] = ss; __syncthreads();
  for (int s = 128; s > 0; s >>= 1) { if (tid < s) red[tid] += red[tid+s]; __syncthreads(); }
  float scale = rsqrtf(red[0]/(float)DM + 1e-6f);
  float* Xr = X + (size_t)row*DM; bf16* Hr = H + (size_t)row*DM;
  #pragma unroll
  for (int i = 0; i < 4; ++i) { Xr[tid*4+i] = v[i]; Hr[tid*4+i] = f2b(v[i]*scale); }
}

// ---------------- fused: X += sum(4 partials); H = bf16(rmsnorm(X)) ----------
// Race-free: each block touches only its own row.
__global__ void k_reduce4_rms(const float* __restrict__ p0, const float* __restrict__ p1,
                              const float* __restrict__ p2, const float* __restrict__ p3,
                              float* __restrict__ X, bf16* __restrict__ H) {
  int row = blockIdx.x; int tid = threadIdx.x;
  size_t base = (size_t)row*DM + tid*4;
  float4 a = *(const float4*)(p0 + base);
  float4 b = *(const float4*)(p1 + base);
  float4 c = *(const float4*)(p2 + base);
  float4 d = *(const float4*)(p3 + base);
  float4 x = *(const float4*)(X + base);
  float v[4];
  v[0] = x.x + a.x + b.x + c.x + d.x;
  v[1] = x.y + a.y + b.y + c.y + d.y;
  v[2] = x.z + a.z + b.z + c.z + d.z;
  v[3] = x.w + a.w + b.w + c.w + d.w;
  float ss = v[0]*v[0] + v[1]*v[1] + v[2]*v[2] + v[3]*v[3];
  __shared__ float red[256];
  red[tid] = ss; __syncthreads();
  for (int s = 128; s > 0; s >>= 1) { if (tid < s) red[tid] += red[tid+s]; __syncthreads(); }
  float scale = rsqrtf(red[0]/(float)DM + 1e-6f);
  float4 res; res.x = v[0]; res.y = v[1]; res.z = v[2]; res.w = v[3];
  *(float4*)(X + base) = res;
  bf16* Hr = H + (size_t)row*DM + tid*4;
  #pragma unroll
  for (int i = 0; i < 4; ++i) Hr[i] = f2b(v[i]*scale);
}

// ---------------- fused rmsnorm + token-shift: X -> XK, XR -------------------
// READ-ONLY on X (the preceding reduce kernel finished writing X) -> race-free.
__global__ void k_rms_shift(const float* __restrict__ X, const float* __restrict__ maak,
                            const float* __restrict__ maar,
                            bf16* __restrict__ XK, bf16* __restrict__ XR) {
  int row = blockIdx.x; int t = row & (TT - 1);
  int tid = threadIdx.x;
  const float* xr = X + (size_t)row*DM;
  const float* xp = xr - DM;
  float v[4], pv[4]; float ss = 0.f, ssp = 0.f;
  #pragma unroll
  for (int i = 0; i < 4; ++i) {
    int c = tid*4 + i;
    v[i] = xr[c]; ss += v[i]*v[i];
    pv[i] = (t > 0) ? xp[c] : 0.f; ssp += pv[i]*pv[i];
  }
  __shared__ float red[256], red2[256];
  red[tid] = ss; red2[tid] = ssp; __syncthreads();
  for (int s = 128; s > 0; s >>= 1) {
    if (tid < s) { red[tid] += red[tid+s]; red2[tid] += red2[tid+s]; }
    __syncthreads();
  }
  float scale  = rsqrtf(red[0]/(float)DM + 1e-6f);
  float scalep = (t > 0) ? rsqrtf(red2[0]/(float)DM + 1e-6f) : 0.f;
  bf16* xk = XK + (size_t)row*DM; bf16* xrw = XR + (size_t)row*DM;
  #pragma unroll
  for (int i = 0; i < 4; ++i) {
    int c = tid*4 + i;
    float h = v[i]*scale;
    float xx = pv[i]*scalep - h;
    xk[c]  = f2b(h + xx*maak[c]);
    xrw[c] = f2b(h + xx*maar[c]);
  }
}

// ---------------- weight cast + transpose: Wt[n][k] = bf16(W[k][n]) ----------
__global__ void k_tcast(const float* __restrict__ W, bf16* __restrict__ Wt,
                        int K, int N) {
  __shared__ float t[32][33];
  int tx = threadIdx.x, ty = threadIdx.y;
  int n0 = blockIdx.x*32, k0 = blockIdx.y*32;
  #pragma unroll
  for (int i = 0; i < 4; ++i) {
    int k = k0 + ty + i*8, n = n0 + tx;
    t[ty + i*8][tx] = (n < N) ? W[(size_t)k*N + n] : 0.f;
  }
  __syncthreads();
  #pragma unroll
  for (int i = 0; i < 4; ++i) {
    int n = n0 + ty + i*8, k = k0 + tx;
    Wt[(size_t)n*K + k] = f2b(t[tx][ty + i*8]);
  }
}

// ---------------- MFMA GEMM 128x128, BK=32, 2-phase pipelined, 8 waves -------
// 512 threads: wave grid 2 (row-halves) x 4 (col-quarters); per-wave MFMA work
// halves (8/iter), per-thread staging = 1 gload16 per operand (wave w stages
// 16-row slab [16w,16w+16), wave-uniform LDS base + lane*16 contract kept).
// 16 waves/CU at 2 blocks/CU hides the ds_read + prefetch latency.
// (BK=64 tried in round 10: +23us regression -- ds_read bytes/barrier doubled
// against the LDS 128B/clk throughput floor. Reverted to this BK=32 form.)
template<int EPI, bool ADD, bool OUTBF>
__global__ __launch_bounds__(512)
void mfma_gemm(const bf16* __restrict__ A, const bf16* __restrict__ Bt,
               float* __restrict__ C, bf16* __restrict__ Cbf,
               int M, int N, int K) {
  __shared__ bf16 As[2][128*32];
  __shared__ bf16 Bs[2][128*32];
  int tid = threadIdx.x;
  int wave = tid >> 6, lane = tid & 63;
  int m_l = lane & 15, quad = lane >> 4;
  int wr = (wave & 1) * 64, wc = (wave >> 1) * 32;
  int row0 = blockIdx.y * 128, col0 = blockIdx.x * 128;
  f32x4 acc[4][2];
  #pragma unroll
  for (int i = 0; i < 4; ++i)
    #pragma unroll
    for (int j = 0; j < 2; ++j) acc[i][j] = (f32x4){0.f,0.f,0.f,0.f};
  int lr = lane >> 2;            // 0..15 row within 16-row slab
  int lc = (lane & 3) * 8;       // 0,8,16,24
  int rbase = 16*wave;
  // prologue: stage tile 0
  gload16(&A [(size_t)(row0 + rbase + lr)*K + lc], &As[0][rbase*32]);
  gload16(&Bt[(size_t)(col0 + rbase + lr)*K + lc], &Bs[0][rbase*32]);
  __syncthreads();
  int nit = K >> 5;
  int cur = 0;
  for (int it = 0; it < nit; ++it) {
    if (it + 1 < nit) {
      int kn = (it + 1) << 5;
      gload16(&A [(size_t)(row0 + rbase + lr)*K + kn + lc], &As[cur^1][rbase*32]);
      gload16(&Bt[(size_t)(col0 + rbase + lr)*K + kn + lc], &Bs[cur^1][rbase*32]);
    }
    bf16x8 af[4], bfv[2];
    #pragma unroll
    for (int i = 0; i < 4; ++i) af[i]  = *(const bf16x8*)&As[cur][(wr + i*16 + m_l)*32 + quad*8];
    #pragma unroll
    for (int j = 0; j < 2; ++j) bfv[j] = *(const bf16x8*)&Bs[cur][(wc + j*16 + m_l)*32 + quad*8];
    #pragma unroll
    for (int i = 0; i < 4; ++i)
      #pragma unroll
      for (int j = 0; j < 2; ++j)
        acc[i][j] = __builtin_amdgcn_mfma_f32_16x16x32_bf16(af[i], bfv[j], acc[i][j], 0, 0, 0);
    __syncthreads();   // drains the prefetch (implicit vmcnt(0)) + syncs
    cur ^= 1;
  }
  #pragma unroll
  for (int i = 0; i < 4; ++i) {
    #pragma unroll
    for (int j = 0; j < 2; ++j) {
      int col = col0 + wc + j*16 + m_l;
      if (col < N) {
        #pragma unroll
        for (int r = 0; r < 4; ++r) {
          int row = row0 + wr + i*16 + quad*4 + r;
          float v = acc[i][j][r];
          if (EPI == 1) { v = fmaxf(v, 0.f); v = v*v; }          // relu^2
          else if (EPI == 2) v = 1.f/(1.f + __expf(-v));          // sigmoid
          if (OUTBF)      Cbf[(size_t)row*N + col] = f2b(v);
          else if (ADD)   C[(size_t)row*N + col] += v;
          else            C[(size_t)row*N + col]  = v;
        }
      }
    }
  }
}

// ---------------- split-K GEMM, BK=32, 2-phase pipelined, 8 waves ------------
__global__ __launch_bounds__(512)
void mfma_sk32(const bf16* __restrict__ A, const bf16* __restrict__ Bt,
               float* __restrict__ P0, float* __restrict__ P1,
               float* __restrict__ P2, float* __restrict__ P3,
               int M, int N, int K, int kchunk) {
  __shared__ bf16 As[2][128*32];
  __shared__ bf16 Bs[2][128*32];
  int tid = threadIdx.x;
  int wave = tid >> 6, lane = tid & 63;
  int m_l = lane & 15, quad = lane >> 4;
  int wr = (wave & 1) * 64, wc = (wave >> 1) * 32;
  int row0 = blockIdx.y * 128, col0 = blockIdx.x * 128;
  int kbeg = blockIdx.z * kchunk;
  f32x4 acc[4][2];
  #pragma unroll
  for (int i = 0; i < 4; ++i)
    #pragma unroll
    for (int j = 0; j < 2; ++j) acc[i][j] = (f32x4){0.f,0.f,0.f,0.f};
  int lr = lane >> 2;            // 0..15
  int lc = (lane & 3) * 8;       // 0,8,16,24
  int rbase = 16*wave;
  // prologue: stage tile kbeg
  gload16(&A [(size_t)(row0 + rbase + lr)*K + kbeg + lc], &As[0][rbase*32]);
  gload16(&Bt[(size_t)(col0 + rbase + lr)*K + kbeg + lc], &Bs[0][rbase*32]);
  __syncthreads();
  int nit = kchunk >> 5;
  int cur = 0;
  for (int it = 0; it < nit; ++it) {
    if (it + 1 < nit) {
      int kn = kbeg + ((it + 1) << 5);
      gload16(&A [(size_t)(row0 + rbase + lr)*K + kn + lc], &As[cur^1][rbase*32]);
      gload16(&Bt[(size_t)(col0 + rbase + lr)*K + kn + lc], &Bs[cur^1][rbase*32]);
    }
    bf16x8 af[4], bfv[2];
    #pragma unroll
    for (int i = 0; i < 4; ++i) af[i]  = *(const bf16x8*)&As[cur][(wr + i*16 + m_l)*32 + quad*8];
    #pragma unroll
    for (int j = 0; j < 2; ++j) bfv[j] = *(const bf16x8*)&Bs[cur][(wc + j*16 + m_l)*32 + quad*8];
    #pragma unroll
    for (int i = 0; i < 4; ++i)
      #pragma unroll
      for (int j = 0; j < 2; ++j)
        acc[i][j] = __builtin_amdgcn_mfma_f32_16x16x32_bf16(af[i], bfv[j], acc[i][j], 0, 0, 0);
    __syncthreads();
    cur ^= 1;
  }
  float* P = (blockIdx.z == 0) ? P0 : (blockIdx.z == 1) ? P1 : (blockIdx.z == 2) ? P2 : P3;
  #pragma unroll
  for (int i = 0; i < 4; ++i) {
    #pragma unroll
    for (int j = 0; j < 2; ++j) {
      int col = col0 + wc + j*16 + m_l;
      if (col < N) {
        #pragma unroll
        for (int r = 0; r < 4; ++r) {
          int row = row0 + wr + i*16 + quad*4 + r;
          P[(size_t)row*N + col] = acc[i][j][r];
        }
      }
    }
  }
}

// ---------------- split-K reduce: dst (+)= epi(sum of Z partials) ------------
template<int Z, int EPI, bool ADD>
__global__ void k_reduce(float* __restrict__ dst, const float* __restrict__ p0,
                         const float* __restrict__ p1, const float* __restrict__ p2,
                         const float* __restrict__ p3) {
  size_t i = ((size_t)blockIdx.x*256 + threadIdx.x)*4;
  float4 a = *(const float4*)(p0 + i);
  float4 b = *(const float4*)(p1 + i);
  float r0 = a.x + b.x, r1 = a.y + b.y, r2 = a.z + b.z, r3 = a.w + b.w;
  if (Z == 4) {
    float4 c = *(const float4*)(p2 + i);
    float4 d = *(const float4*)(p3 + i);
    r0 += c.x + d.x; r1 += c.y + d.y; r2 += c.z + d.z; r3 += c.w + d.w;
  }
  if (EPI == 2) {
    r0 = 1.f/(1.f + __expf(-r0)); r1 = 1.f/(1.f + __expf(-r1));
    r2 = 1.f/(1.f + __expf(-r2)); r3 = 1.f/(1.f + __expf(-r3));
  }
  if (ADD) {
    float4 o = *(const float4*)(dst + i);
    r0 += o.x; r1 += o.y; r2 += o.z; r3 += o.w;
  }
  float4 res; res.x = r0; res.y = r1; res.z = r2; res.w = r3;
  *(float4*)(dst + i) = res;
}

// -------- fused: out = X + sigmoid(r0+r1) * (k0+k1+k2+k3) --------------------
__global__ void k_reduce_final6(const float* __restrict__ k0, const float* __restrict__ k1,
                                const float* __restrict__ k2, const float* __restrict__ k3,
                                const float* __restrict__ r0p, const float* __restrict__ r1p,
                                const float* __restrict__ X, float* __restrict__ out) {
  size_t i = ((size_t)blockIdx.x*256 + threadIdx.x)*4;
  float4 a = *(const float4*)(k0 + i);
  float4 b = *(const float4*)(k1 + i);
  float4 c = *(const float4*)(k2 + i);
  float4 d = *(const float4*)(k3 + i);
  float4 ra = *(const float4*)(r0p + i);
  float4 rb = *(const float4*)(r1p + i);
  float4 x = *(const float4*)(X + i);
  float kvx = a.x + b.x + c.x + d.x, kvy = a.y + b.y + c.y + d.y;
  float kvz = a.z + b.z + c.z + d.z, kvw = a.w + b.w + c.w + d.w;
  float sx = 1.f/(1.f + __expf(-(ra.x + rb.x)));
  float sy = 1.f/(1.f + __expf(-(ra.y + rb.y)));
  float sz = 1.f/(1.f + __expf(-(ra.z + rb.z)));
  float sw = 1.f/(1.f + __expf(-(ra.w + rb.w)));
  float4 res;
  res.x = x.x + sx*kvx; res.y = x.y + sy*kvy;
  res.z = x.z + sz*kvz; res.w = x.w + sw*kvw;
  *(float4*)(out + i) = res;
}

// ---------------- SSM conv (K=4) + silu + dt softplus; bf16 xBC out ----------
__global__ void k_conv_ssm(const float* __restrict__ ZXr, const float* __restrict__ cw,
                           const float* __restrict__ cb, const float* __restrict__ dtb,
                           bf16* __restrict__ XBCb, float* __restrict__ DT) {
  int bt = blockIdx.x; int b = bt >> 10; int t = bt & 1023;
  int tid = threadIdx.x;
  for (int c = tid; c < NXBC; c += 256) {
    float acc = cb[c];
    #pragma unroll
    for (int kk = 0; kk < 4; ++kk) {
      int ts = t - 3 + kk;
      if (ts >= 0) acc += cw[c*4+kk] * ZXr[((size_t)(b*TT+ts))*NXBCD + c];
    }
    float s = acc / (1.f + __expf(-acc));  // silu
    XBCb[(size_t)bt*NXBC + c] = f2b(s);
  }
  if (tid < NHS) {
    float x = ZXr[(size_t)bt*NXBCD + NXBC + tid] + dtb[tid];
    float sp = (x > 20.f) ? x : log1pf(__expf(x));
    DT[(size_t)bt*NHS + tid] = sp;
  }
}

// ---------------- scan pass 1: intra-chunk via MFMA, 8 waves -----------------
__global__ __launch_bounds__(512)
void k_scan1(const bf16* __restrict__ xbcb, const float* __restrict__ dt,
             const float* __restrict__ A_log, const float* __restrict__ Dmv,
             float* __restrict__ Y, float* __restrict__ SC, float* __restrict__ CUM) {
  int bc = blockIdx.x;
  int bh = bc >> 3, c = bc & 7;
  int b = bh >> 5, h = bh & 31;
  int tid = threadIdx.x, wave = tid >> 6, lane = tid & 63;
  int col = lane & 15, quad = lane >> 4;
  int t0 = c * CL;
  __shared__ bf16 sB[128*136];   // B rows [s][n]; later BwT [n][s]
  __shared__ bf16 sC[128*136];   // C rows [t][n]; later Ps [t][s]
  __shared__ bf16 sxT[64*136];   // x^T [p][t]
  __shared__ float sL[128], sdt[128], sW[128];
  float A = -__expf(A_log[h]);
  float Dmh = Dmv[h];
  for (int e = tid; e < 128*16; e += 512) {
    int r = e >> 4, ch = e & 15;
    const bf16* row = xbcb + (size_t)(b*TT + t0 + r)*NXBC;
    *(uint4*)&sB[r*136 + ch*8] = *(const uint4*)&row[2048 + ch*8];
    *(uint4*)&sC[r*136 + ch*8] = *(const uint4*)&row[2176 + ch*8];
  }
  for (int e = tid; e < 64*128; e += 512) {
    int p = e & 63, t = e >> 6;
    sxT[p*136 + t] = xbcb[(size_t)(b*TT + t0 + t)*NXBC + h*64 + p];
  }
  if (tid < 128) sdt[tid] = dt[(size_t)(b*TT + t0 + tid)*NHS + h];
  __syncthreads();
  if (wave == 0) {
    float a0 = sdt[2*lane]*A, a1 = sdt[2*lane+1]*A;
    float tot = a0 + a1;
    #pragma unroll
    for (int off = 1; off < 64; off <<= 1) {
      float up = __shfl_up(tot, off);
      if (lane >= off) tot += up;
    }
    sL[2*lane+1] = tot;
    sL[2*lane]   = tot - a1;
  }
  __syncthreads();
  // MFMA1: g[t][s] = C @ B^T; wave tiling 2 (t-halves) x 4 (s-quarters)
  int wr = (wave & 1)*64, wc = (wave >> 1)*32;
  f32x4 g[4][2];
  #pragma unroll
  for (int i = 0; i < 4; ++i)
    #pragma unroll
    for (int j = 0; j < 2; ++j) g[i][j] = (f32x4){0.f,0.f,0.f,0.f};
  #pragma unroll
  for (int kf = 0; kf < 4; ++kf) {
    bf16x8 af[4], bfr[2];
    #pragma unroll
    for (int i = 0; i < 4; ++i) af[i]  = *(const bf16x8*)&sC[(wr + i*16 + col)*136 + kf*32 + quad*8];
    #pragma unroll
    for (int j = 0; j < 2; ++j) bfr[j] = *(const bf16x8*)&sB[(wc + j*16 + col)*136 + kf*32 + quad*8];
    #pragma unroll
    for (int i = 0; i < 4; ++i)
      #pragma unroll
      for (int j = 0; j < 2; ++j)
        g[i][j] = __builtin_amdgcn_mfma_f32_16x16x32_bf16(af[i], bfr[j], g[i][j], 0, 0, 0);
  }
  float Lend = sL[127];
  if (tid < 128) sW[tid] = __expf(Lend - sL[tid]) * sdt[tid];
  __syncthreads();
  if (tid < 128) CUM[(size_t)bh*TT + t0 + tid] = __expf(sL[tid]);
  #pragma unroll
  for (int i = 0; i < 4; ++i) {
    #pragma unroll
    for (int j = 0; j < 2; ++j) {
      int sl = wc + j*16 + col;
      #pragma unroll
      for (int r = 0; r < 4; ++r) {
        int tl = wr + i*16 + quad*4 + r;
        float v = (sl <= tl) ? g[i][j][r] * __expf(sL[tl] - sL[sl]) * sdt[sl] : 0.f;
        sC[tl*136 + sl] = f2b(v);
      }
    }
  }
  for (int e = tid; e < 128*128; e += 512) {
    int n = e & 127, s = e >> 7;
    sB[n*136 + s] = f2b(b2f(xbcb[(size_t)(b*TT + t0 + s)*NXBC + 2048 + n]) * sW[s]);
  }
  __syncthreads();
  // MFMA2: y[t][p] = Ps @ x^T^T; wave tiling 4 (t-quarters) x 2 (p-halves)
  int tb = (wave & 3)*32, pb = (wave >> 2)*32;
  f32x4 ya[2][2];
  #pragma unroll
  for (int i2 = 0; i2 < 2; ++i2)
    #pragma unroll
    for (int jd = 0; jd < 2; ++jd) ya[i2][jd] = (f32x4){0.f,0.f,0.f,0.f};
  #pragma unroll
  for (int kf = 0; kf < 4; ++kf) {
    bf16x8 pa[2], xa[2];
    #pragma unroll
    for (int i2 = 0; i2 < 2; ++i2)
      pa[i2] = *(const bf16x8*)&sC[(tb + i2*16 + col)*136 + kf*32 + quad*8];
    #pragma unroll
    for (int jd = 0; jd < 2; ++jd)
      xa[jd] = *(const bf16x8*)&sxT[(pb + jd*16 + col)*136 + kf*32 + quad*8];
    #pragma unroll
    for (int i2 = 0; i2 < 2; ++i2)
      #pragma unroll
      for (int jd = 0; jd < 2; ++jd)
        ya[i2][jd] = __builtin_amdgcn_mfma_f32_16x16x32_bf16(pa[i2], xa[jd], ya[i2][jd], 0, 0, 0);
  }
  #pragma unroll
  for (int i2 = 0; i2 < 2; ++i2) {
    #pragma unroll
    for (int jd = 0; jd < 2; ++jd) {
      int p = pb + jd*16 + col;
      #pragma unroll
      for (int r = 0; r < 4; ++r) {
        int tl = tb + i2*16 + quad*4 + r;
        float xv = b2f(sxT[p*136 + tl]);
        Y[(size_t)(b*TT + t0 + tl)*DI + h*64 + p] = ya[i2][jd][r] + xv*Dmh;
      }
    }
  }
  // MFMA3: SC[p][n] = x^T @ Bw^T; wave tiling 4 (p-16-blocks) x 2 (n-halves)
  int pb3 = (wave & 3)*16, nb = (wave >> 2)*64;
  f32x4 sa[4];
  #pragma unroll
  for (int nt = 0; nt < 4; ++nt) sa[nt] = (f32x4){0.f,0.f,0.f,0.f};
  #pragma unroll
  for (int kf = 0; kf < 4; ++kf) {
    bf16x8 xpa = *(const bf16x8*)&sxT[(pb3 + col)*136 + kf*32 + quad*8];
    #pragma unroll
    for (int nt = 0; nt < 4; ++nt) {
      bf16x8 bwa = *(const bf16x8*)&sB[(nb + nt*16 + col)*136 + kf*32 + quad*8];
      sa[nt] = __builtin_amdgcn_mfma_f32_16x16x32_bf16(xpa, bwa, sa[nt], 0, 0, 0);
    }
  }
  #pragma unroll
  for (int nt = 0; nt < 4; ++nt) {
    int n = nb + nt*16 + col;
    #pragma unroll
    for (int r = 0; r < 4; ++r) {
      int p = pb3 + quad*4 + r;
      SC[((size_t)(bh*NC + c)*64 + p)*128 + n] = sa[nt][r];
    }
  }
}

// ---------------- scan pass 2: sequential inter-chunk combine (fp32) ---------
__global__ __launch_bounds__(512)
void k_scan2(float* __restrict__ SC, const float* __restrict__ CUM) {
  int bh = blockIdx.x;
  int tid = threadIdx.x;
  int p = tid >> 3, g = tid & 7;
  float S[16];
  #pragma unroll
  for (int j = 0; j < 16; ++j) S[j] = 0.f;
  for (int c = 0; c < NC; ++c) {
    size_t base = ((size_t)(bh*NC + c)*64 + p)*128 + g*16;
    float Ptot = CUM[(size_t)bh*TT + c*CL + (CL-1)];
    float tmp[16];
    #pragma unroll
    for (int j = 0; j < 16; ++j) tmp[j] = SC[base + j];
    #pragma unroll
    for (int j = 0; j < 16; ++j) SC[base + j] = S[j];
    #pragma unroll
    for (int j = 0; j < 16; ++j) S[j] = S[j]*Ptot + tmp[j];
  }
}

// ---------------- scan pass 3: Y += CUM[t] * (C @ S_init^T) via MFMA ---------
__global__ __launch_bounds__(256)
void k_scan3(const bf16* __restrict__ xbcb, const float* __restrict__ SC,
             const float* __restrict__ CUM, float* __restrict__ Y) {
  int bc = blockIdx.x;
  int bh = bc >> 3, c = bc & 7;
  if (c == 0) return;
  int b = bh >> 5, h = bh & 31;
  int tid = threadIdx.x, wave = tid >> 6, lane = tid & 63;
  int col = lane & 15, quad = lane >> 4;
  int t0 = c * CL;
  __shared__ bf16 sCt[128*136];
  __shared__ bf16 sS[64*136];
  __shared__ float sCum[128];
  for (int e = tid; e < 128*16; e += 256) {
    int r = e >> 4, ch = e & 15;
    *(uint4*)&sCt[r*136 + ch*8] =
      *(const uint4*)&xbcb[(size_t)(b*TT + t0 + r)*NXBC + 2176 + ch*8];
  }
  for (int e = tid; e < 64*128; e += 256) {
    int n = e & 127, p = e >> 7;
    sS[p*136 + n] = f2b(SC[((size_t)(bh*NC + c)*64 + p)*128 + n]);
  }
  if (tid < 128) sCum[tid] = CUM[(size_t)bh*TT + t0 + tid];
  __syncthreads();
  f32x4 ya[2][4];
  #pragma unroll
  for (int i2 = 0; i2 < 2; ++i2)
    #pragma unroll
    for (int jd = 0; jd < 4; ++jd) ya[i2][jd] = (f32x4){0.f,0.f,0.f,0.f};
  #pragma unroll
  for (int kf = 0; kf < 4; ++kf) {
    bf16x8 pa[2], sv[4];
    #pragma unroll
    for (int i2 = 0; i2 < 2; ++i2)
      pa[i2] = *(const bf16x8*)&sCt[(wave*32 + i2*16 + col)*136 + kf*32 + quad*8];
    #pragma unroll
    for (int jd = 0; jd < 4; ++jd)
      sv[jd] = *(const bf16x8*)&sS[(jd*16 + col)*136 + kf*32 + quad*8];
    #pragma unroll
    for (int i2 = 0; i2 < 2; ++i2)
      #pragma unroll
      for (int jd = 0; jd < 4; ++jd)
        ya[i2][jd] = __builtin_amdgcn_mfma_f32_16x16x32_bf16(pa[i2], sv[jd], ya[i2][jd], 0, 0, 0);
  }
  #pragma unroll
  for (int i2 = 0; i2 < 2; ++i2) {
    #pragma unroll
    for (int jd = 0; jd < 4; ++jd) {
      int p = jd*16 + col;
      #pragma unroll
      for (int r = 0; r < 4; ++r) {
        int tl = wave*32 + i2*16 + quad*4 + r;
        Y[(size_t)(b*TT + t0 + tl)*DI + h*64 + p] += sCum[tl]*ya[i2][jd][r];
      }
    }
  }
}

// ---------------- gate: Ybf = bf16(rmsnorm(y * silu(z)) * mnorm_w) -----------
__global__ void k_gate(const float* __restrict__ Y, const float* __restrict__ Z,
                       const float* __restrict__ mnw, bf16* __restrict__ Ybf) {
  int row = blockIdx.x; int tid = threadIdx.x;
  const float* yr = Y + (size_t)row*DI;
  const float* zr = Z + (size_t)row*DI;
  float gv[8]; float ss = 0.f;
  #pragma unroll
  for (int i = 0; i < 8; ++i) {
    int c = tid*8 + i;
    float z = zr[c];
    float sz = z / (1.f + __expf(-z));
    float v = yr[c]*sz;
    gv[i] = v; ss += v*v;
  }
  __shared__ float red[256];
  red[tid] = ss; __syncthreads();
  for (int s = 128; s > 0; s >>= 1) { if (tid < s) red[tid] += red[tid+s]; __syncthreads(); }
  float scale = rsqrtf(red[0]/(float)DI + 1e-5f);
  bf16* br = Ybf + (size_t)row*DI;
  #pragma unroll
  for (int i = 0; i < 8; ++i) { int c = tid*8 + i; br[c] = f2b(gv[i]*scale*mnw[c]); }
}

// ------ q/k/v causal dwconv (K=3) with FUSED split-K reduce of QKV -----------
__global__ void k_conv_qkv(const float* __restrict__ P0, const float* __restrict__ P1,
                           const float* qw, const float* qb, const float* kw, const float* kb,
                           const float* vw, const float* vb,
                           bf16* __restrict__ Qb, bf16* __restrict__ Kb, bf16* __restrict__ Vtb) {
  int bt = blockIdx.x; int b = bt >> 10; int t = bt & 1023;
  int tid = threadIdx.x;
  for (int c = tid; c < 1152; c += 256) {
    if (c < 1024) {
      int h = c >> 6, d = c & 63;
      float acc = qb[d];
      #pragma unroll
      for (int kk = 0; kk < 3; ++kk) {
        int ts = t-2+kk;
        if (ts >= 0) { size_t ix = ((size_t)(b*TT+ts))*1152 + c; acc += qw[d*3+kk] * (P0[ix] + P1[ix]); }
      }
      Qb[((size_t)(b*NHA + h)*TT + t)*HD + d] = f2b(acc * 0.125f);  // 1/sqrt(64)
    } else if (c < 1088) {
      int d = c - 1024;
      float acc = kb[d];
      #pragma unroll
      for (int kk = 0; kk < 3; ++kk) {
        int ts = t-2+kk;
        if (ts >= 0) { size_t ix = ((size_t)(b*TT+ts))*1152 + c; acc += kw[d*3+kk] * (P0[ix] + P1[ix]); }
      }
      Kb[(size_t)bt*HD + d] = f2b(acc);
    } else {
      int d = c - 1088;
      float acc = vb[d];
      #pragma unroll
      for (int kk = 0; kk < 3; ++kk) {
        int ts = t-2+kk;
        if (ts >= 0) { size_t ix = ((size_t)(b*TT+ts))*1152 + c; acc += vw[d*3+kk] * (P0[ix] + P1[ix]); }
      }
      Vtb[((size_t)(b*HD + d))*TT + t] = f2b(acc);
    }
  }
}

// ---------------- split-KV MFMA flash attention, max-free, 8 waves -----------
__global__ __launch_bounds__(512)
void k_flash_sk(const bf16* __restrict__ Qb, const bf16* __restrict__ Kb,
                const bf16* __restrict__ Vtb, float* __restrict__ Op,
                float* __restrict__ Lp) {
  int qt = blockIdx.x >> 1, z = blockIdx.x & 1;
  int h = blockIdx.y, b = blockIdx.z;
  int n = qt + 1;
  int kmid = (n + 1) >> 1;
  int kbeg = z ? kmid : 0;
  int kend = z ? n : kmid;
  int tid = threadIdx.x, wave = tid >> 6, lane = tid & 63;
  int col = lane & 15, quad = lane >> 4;
  int t0 = qt * 128;
  __shared__ bf16 Ks[128*72];
  __shared__ bf16 Vs[64*136];
  __shared__ bf16 Ps[8][16*136];
  const bf16* Qbase = Qb + ((size_t)(b*NHA + h))*TT*HD;
  float lst[4];
  f32x4 oacc[4];
  #pragma unroll
  for (int r = 0; r < 4; ++r) lst[r] = 0.f;
  #pragma unroll
  for (int jd = 0; jd < 4; ++jd) oacc[jd] = (f32x4){0.f,0.f,0.f,0.f};
  if (kbeg < kend) {
    bf16x8 qf[2];
    #pragma unroll
    for (int kf = 0; kf < 2; ++kf)
      qf[kf] = *(const bf16x8*)&Qbase[(size_t)(t0 + wave*16 + col)*HD + kf*32 + quad*8];

    for (int kt = kbeg; kt < kend; ++kt) {
      int s0 = kt * 128;
      __syncthreads();
      for (int e = tid; e < 1024; e += 512) {
        int r = e >> 3, ch = e & 7;
        *(uint4*)&Ks[r*72 + ch*8] = *(const uint4*)&Kb[((size_t)(b*TT + s0 + r))*HD + ch*8];
      }
      for (int e = tid; e < 1024; e += 512) {
        int d = e >> 4, ch = e & 15;
        *(uint4*)&Vs[d*136 + ch*8] = *(const uint4*)&Vtb[((size_t)(b*HD + d))*TT + s0 + ch*8];
      }
      __syncthreads();
      f32x4 sacc[8];
      #pragma unroll
      for (int j = 0; j < 8; ++j) sacc[j] = (f32x4){0.f,0.f,0.f,0.f};
      __builtin_amdgcn_s_setprio(1);
      #pragma unroll
      for (int j = 0; j < 8; ++j) {
        bf16x8 kf0 = *(const bf16x8*)&Ks[(j*16 + col)*72 + quad*8];
        bf16x8 kf1 = *(const bf16x8*)&Ks[(j*16 + col)*72 + 32 + quad*8];
        sacc[j] = __builtin_amdgcn_mfma_f32_16x16x32_bf16(qf[0], kf0, sacc[j], 0, 0, 0);
        sacc[j] = __builtin_amdgcn_mfma_f32_16x16x32_bf16(qf[1], kf1, sacc[j], 0, 0, 0);
      }
      __builtin_amdgcn_s_setprio(0);
      bool diag = (kt == qt);
      #pragma unroll
      for (int r = 0; r < 4; ++r) {
        int rowloc = wave*16 + quad*4 + r;
        #pragma unroll
        for (int j = 0; j < 8; ++j) {
          float pv = __expf(sacc[j][r]);
          if (diag && (j*16 + col > rowloc)) pv = 0.f;
          sacc[j][r] = pv;
          lst[r] += pv;
        }
      }
      #pragma unroll
      for (int j = 0; j < 8; ++j)
        #pragma unroll
        for (int r = 0; r < 4; ++r)
          Ps[wave][(quad*4 + r)*136 + j*16 + col] = f2b(sacc[j][r]);
      __builtin_amdgcn_s_setprio(1);
      bf16x8 pa[4];
      #pragma unroll
      for (int kf = 0; kf < 4; ++kf)
        pa[kf] = *(const bf16x8*)&Ps[wave][col*136 + kf*32 + quad*8];
      #pragma unroll
      for (int jd = 0; jd < 4; ++jd) {
        #pragma unroll
        for (int kf = 0; kf < 4; ++kf) {
          bf16x8 vbf = *(const bf16x8*)&Vs[(jd*16 + col)*136 + kf*32 + quad*8];
          oacc[jd] = __builtin_amdgcn_mfma_f32_16x16x32_bf16(pa[kf], vbf, oacc[jd], 0, 0, 0);
        }
      }
      __builtin_amdgcn_s_setprio(0);
    }
    #pragma unroll
    for (int r = 0; r < 4; ++r) {
      float l = lst[r];
      l += __shfl_xor(l, 1);
      l += __shfl_xor(l, 2);
      l += __shfl_xor(l, 4);
      l += __shfl_xor(l, 8);
      lst[r] = l;
    }
  }
  if (qt == 0 && z == 1) return;
  size_t robase = ((size_t)((z*BB + b)*NHA + h))*TT + t0;
  #pragma unroll
  for (int jd = 0; jd < 4; ++jd) {
    int d = jd*16 + col;
    #pragma unroll
    for (int r = 0; r < 4; ++r) {
      int tl = wave*16 + quad*4 + r;
      Op[(robase + tl)*HD + d] = oacc[jd][r];
    }
  }
  if (col == 0) {
    #pragma unroll
    for (int r = 0; r < 4; ++r) {
      int tl = wave*16 + quad*4 + r;
      Lp[robase + tl] = lst[r];
    }
  }
}

// ---------------- attention split-KV combine (max-free: pure sums) -----------
__global__ void k_att_comb(const float* __restrict__ Op, const float* __restrict__ Lp,
                           bf16* __restrict__ outb) {
  int idx = blockIdx.x*256 + threadIdx.x;   // one thread = 4 consecutive d
  int e = idx*4;
  int c = e & (DM - 1); int h = c >> 6; int d = c & 63;
  int bt = e >> 10; int t = bt & (TT - 1); int b = bt >> 10;
  int qt = t >> 7;
  size_t r0 = ((size_t)(b*NHA + h))*TT + t;
  float4 o0 = *(const float4*)&Op[r0*HD + d];
  float l = Lp[r0];
  float ox = o0.x, oy = o0.y, oz = o0.z, ow = o0.w;
  if (qt > 0) {
    size_t r1 = ((size_t)((BB + b)*NHA + h))*TT + t;
    float4 o1 = *(const float4*)&Op[r1*HD + d];
    l += Lp[r1];
    ox += o1.x; oy += o1.y; oz += o1.z; ow += o1.w;
  }
  float inv = 1.f / l;
  bf16* p = outb + (size_t)bt*DM + c;
  p[0] = f2b(ox*inv); p[1] = f2b(oy*inv); p[2] = f2b(oz*inv); p[3] = f2b(ow*inv);
}

// =============================================================================
extern "C" void kernel_launch(void* const* d_in, const int* in_sizes, int n_in,
                              void* d_out, int out_size, void* d_ws, size_t ws_size,
                              hipStream_t stream) {
  const float* x_in    = (const float*)d_in[0];
  const float* W_in    = (const float*)d_in[1];
  const float* conv_w  = (const float*)d_in[2];
  const float* conv_b  = (const float*)d_in[3];
  const float* A_log   = (const float*)d_in[4];
  const float* Dm      = (const float*)d_in[5];
  const float* dt_bias = (const float*)d_in[6];
  const float* mnorm_w = (const float*)d_in[7];
  const float* W_out   = (const float*)d_in[8];
  const float* W_qkv   = (const float*)d_in[9];
  const float* W_cproj = (const float*)d_in[10];
  const float* qconv_w = (const float*)d_in[11];
  const float* qconv_b = (const float*)d_in[12];
  const float* kconv_w = (const float*)d_in[13];
  const float* kconv_b = (const float*)d_in[14];
  const float* vconv_w = (const float*)d_in[15];
  const float* vconv_b = (const float*)d_in[16];
  const float* maa_k   = (const float*)d_in[17];
  const float* maa_r   = (const float*)d_in[18];
  const float* W_key   = (const float*)d_in[19];
  const float* W_rec   = (const float*)d_in[20];
  const float* W_val   = (const float*)d_in[21];
  float* out = (float*)d_out;

  float* ws = (float*)d_ws;
  float* X       = ws;                       // [0, 2,097,152)
  bf16*  Hbf     = (bf16*)(ws + 2097152);    // 2,097,152 bf16
  float* Zbuf    = ws + 3145728;             // [3,145,728, 7,340,032)
  float* XBCDraw = ws + 7340032;             // [7,340,032, 12,124,160)
  float* XBC     = ws + 12124160;            // [12,124,160, 16,842,752)
  float* DT      = ws + 16842752;            // +65,536
  float* CUM     = ws + 16908288;            // +65,536
  float* Y       = ws + 16973824;            // [16,973,824, 21,168,128)

  bf16*  Wt_in    = (bf16*)XBC;
  bf16*  XBCb     = (bf16*)XBC;
  float* SC       = XBCDraw;
  bf16*  Ybf      = (bf16*)XBC;
  bf16*  Wt_out   = (bf16*)(XBC + 2097152);
  bf16*  Wt_qkv   = (bf16*)XBC;
  bf16*  Qb       = (bf16*)XBCDraw;
  bf16*  Kb       = (bf16*)(XBCDraw + 1048576);
  bf16*  Vtb      = (bf16*)(XBCDraw + 1114112);
  bf16*  ATTNbf   = (bf16*)Y;
  bf16*  Wt_cproj = (bf16*)(Y + 1048576);
  bf16*  XKbf     = (bf16*)XBC;
  bf16*  XRbf     = (bf16*)(XBC + 1048576);
  bf16*  Wt_key   = (bf16*)Zbuf;
  bf16*  KFbf     = (bf16*)XBCDraw;
  bf16*  Wt_val   = (bf16*)Zbuf;
  bf16*  Wt_rec   = (bf16*)Zbuf;
  // flash split-KV partials (live only between k_conv_qkv and k_att_comb):
  float* FOp      = Zbuf;                    // 2 x 2,097,152 fp32
  float* FLp      = ws + 2097152;            // 65,536 (Hbf region, dead here)

  dim3 thr256(256), thr512(512);
  dim3 tblk(32, 8);

  // 1. X = x; Hbf = rmsnorm(x)
  k_rms_in<<<BT, thr256, 0, stream>>>(x_in, X, Hbf);
  // 2. [Z | XBCDraw] = Hbf @ W_in  (wide, full-K)
  k_tcast<<<dim3(4480/32, 1024/32), tblk, 0, stream>>>(W_in, Wt_in, 1024, NZX);
  mfma_gemm<0,false,false><<<dim3(16, 16), thr512, 0, stream>>>(Hbf, Wt_in, Zbuf, nullptr, BT, 2048, 1024);
  mfma_gemm<0,false,false><<<dim3(19, 16), thr512, 0, stream>>>(Hbf, Wt_in + (size_t)2048*1024, XBCDraw, nullptr, BT, NXBCD, 1024);
  // 3. conv+silu on xBC (bf16 out), softplus dt
  k_conv_ssm<<<BT, thr256, 0, stream>>>(XBCDraw, conv_w, conv_b, dt_bias, XBCb, DT);
  // 4. SSM chunked scan via MFMA (scan1 8 waves)
  k_scan1<<<BB*NHS*NC, thr512, 0, stream>>>(XBCb, DT, A_log, Dm, Y, SC, CUM);
  k_scan2<<<BB*NHS, thr512, 0, stream>>>(SC, CUM);
  k_scan3<<<BB*NHS*NC, thr256, 0, stream>>>(XBCb, SC, CUM, Y);
  // 5. gate + mnorm -> Ybf
  k_gate<<<BT, thr256, 0, stream>>>(Y, Zbuf, mnorm_w, Ybf);
  // 6+7. X += Ybf @ W_out (split-K z=4) -> fused reduce + rmsnorm -> Hbf
  k_tcast<<<dim3(1024/32, 2048/32), tblk, 0, stream>>>(W_out, Wt_out, 2048, 1024);
  mfma_sk32<<<dim3(8, 16, 4), thr512, 0, stream>>>(Ybf, Wt_out,
      Zbuf, Zbuf + 2097152, XBCDraw, XBCDraw + 2097152, BT, 1024, 2048, 512);
  k_reduce4_rms<<<BT, thr256, 0, stream>>>(Zbuf, Zbuf + 2097152, XBCDraw, XBCDraw + 2097152, X, Hbf);
  // 8. QKV partials = Hbf @ W_qkv (split-K z=2; p0 -> Zbuf, p1 -> Y;
  //    reduce FUSED into conv_qkv)
  k_tcast<<<dim3(1152/32, 1024/32), tblk, 0, stream>>>(W_qkv, Wt_qkv, 1024, 1152);
  mfma_sk32<<<dim3(9, 16, 2), thr512, 0, stream>>>(Hbf, Wt_qkv,
      Zbuf, Y, Zbuf, Zbuf, BT, 1152, 1024, 512);
  // 9. q/k/v convs (fused QKV reduce) -> bf16 Qb (scaled), Kb, Vtb (transposed)
  k_conv_qkv<<<BT, thr256, 0, stream>>>(Zbuf, Y, qconv_w, qconv_b, kconv_w, kconv_b, vconv_w, vconv_b, Qb, Kb, Vtb);
  // 10. split-KV max-free flash attention (8 waves) -> partials -> combine
  k_flash_sk<<<dim3((TT/128)*2, NHA, BB), thr512, 0, stream>>>(Qb, Kb, Vtb, FOp, FLp);
  k_att_comb<<<(BT*DM)/(256*4), thr256, 0, stream>>>(FOp, FLp, ATTNbf);
  // 11. X += ATTNbf @ W_cproj (split-K z=2, partials in Zbuf); separate reduce
  k_tcast<<<dim3(1024/32, 1024/32), tblk, 0, stream>>>(W_cproj, Wt_cproj, 1024, 1024);
  mfma_sk32<<<dim3(8, 16, 2), thr512, 0, stream>>>(ATTNbf, Wt_cproj,
      Zbuf, Zbuf + 2097152, Zbuf, Zbuf, BT, 1024, 1024, 512);
  k_reduce<2,0,true><<<2048, thr256, 0, stream>>>(X, Zbuf, Zbuf + 2097152, Zbuf, Zbuf);
  // 12+13. fused rmsnorm + token shift (READ-ONLY on X) -> XKbf, XRbf
  k_rms_shift<<<BT, thr256, 0, stream>>>(X, maa_k, maa_r, XKbf, XRbf);
  // 14. KFbf = bf16(relu(XKbf @ W_key)^2)  (wide, full-K, 512 blocks)
  k_tcast<<<dim3(4096/32, 1024/32), tblk, 0, stream>>>(W_key, Wt_key, 1024, 4096);
  mfma_gemm<1,false,true><<<dim3(32, 16), thr512, 0, stream>>>(XKbf, Wt_key, nullptr, KFbf, BT, 4096, 1024);
  // 15. KV partials = KFbf @ W_val  (split-K z=4; NO reduce -- fused into final)
  k_tcast<<<dim3(1024/32, 4096/32), tblk, 0, stream>>>(W_val, Wt_val, 4096, 1024);
  mfma_sk32<<<dim3(8, 16, 4), thr512, 0, stream>>>(KFbf, Wt_val,
      Y, Y + 2097152, XBC + 2621440, Zbuf + 2097152, BT, 1024, 4096, 1024);
  // 16. R partials = XRbf @ W_rec (split-K z=2 -> XBCDraw; KFbf dead)
  k_tcast<<<dim3(1024/32, 1024/32), tblk, 0, stream>>>(W_rec, Wt_rec, 1024, 1024);
  mfma_sk32<<<dim3(8, 16, 2), thr512, 0, stream>>>(XRbf, Wt_rec,
      XBCDraw, XBCDraw + 2097152, XBCDraw, XBCDraw, BT, 1024, 1024, 512);
  // 17. fused: out = X + sigmoid(r0+r1) * (k0+k1+k2+k3)
  k_reduce_final6<<<2048, thr256, 0, stream>>>(
      Y, Y + 2097152, XBC + 2621440, Zbuf + 2097152,
      XBCDraw, XBCDraw + 2097152, X, out);
}

// Round 13
// 492.845 us; speedup vs baseline: 1.0481x; 1.0067x over previous
//
#include <hip/hip_runtime.h>
#include <hip/hip_bf16.h>
#include <math.h>

#define BB 2
#define TT 1024
#define BT (BB*TT)          // 2048 rows
#define DM 1024
#define DI 2048
#define DS 128
#define NHS 32              // ssm heads
#define PDIM 64             // ssm headdim
#define NHA 16              // attn heads
#define HD 64
#define FFN_ 4096
#define NZX 4384            // 2*DI + 2*DS + NHS
#define NXBC 2304           // DI + 2*DS
#define NXBCD 2336          // xBC (2304) + dt (32) raw gemm-out width
#define CL 128              // scan chunk length
#define NC 8                // chunks

typedef __hip_bfloat16 bf16;
typedef short bf16x8 __attribute__((ext_vector_type(8)));
typedef float f32x4 __attribute__((ext_vector_type(4)));

__device__ __forceinline__ float b2f(bf16 v){ return __bfloat162float(v); }
__device__ __forceinline__ bf16 f2b(float v){ return __float2bfloat16(v); }

// async global->LDS, 16B per lane; LDS dest = wave-uniform base + lane*16
__device__ __forceinline__ void gload16(const void* g, void* l) {
  __builtin_amdgcn_global_load_lds(
      (const __attribute__((address_space(1))) unsigned int*)g,
      (__attribute__((address_space(3))) unsigned int*)l,
      16, 0, 0);
}

// ---------------- RMSNorm: write fp32 X copy + bf16 normalized H -------------
__global__ void k_rms_in(const float* __restrict__ xin, float* __restrict__ X,
                         bf16* __restrict__ H) {
  int row = blockIdx.x;
  int tid = threadIdx.x;          // 256 threads, 4 elems each (DM=1024)
  const float* xr = xin + (size_t)row * DM;
  float v[4]; float ss = 0.f;
  #pragma unroll
  for (int i = 0; i < 4; ++i) { v[i] = xr[tid*4+i]; ss += v[i]*v[i]; }
  __shared__ float red[256];
  red[tid] = ss; __syncthreads();
  for (int s = 128; s > 0; s >>= 1) { if (tid < s) red[tid] += red[tid+s]; __syncthreads(); }
  float scale = rsqrtf(red[0]/(float)DM + 1e-6f);
  float* Xr = X + (size_t)row*DM; bf16* Hr = H + (size_t)row*DM;
  #pragma unroll
  for (int i = 0; i < 4; ++i) { Xr[tid*4+i] = v[i]; Hr[tid*4+i] = f2b(v[i]*scale); }
}

// ---------------- fused: X += sum(4 partials); H = bf16(rmsnorm(X)) ----------
// Race-free: each block touches only its own row.
__global__ void k_reduce4_rms(const float* __restrict__ p0, const float* __restrict__ p1,
                              const float* __restrict__ p2, const float* __restrict__ p3,
                              float* __restrict__ X, bf16* __restrict__ H) {
  int row = blockIdx.x; int tid = threadIdx.x;
  size_t base = (size_t)row*DM + tid*4;
  float4 a = *(const float4*)(p0 + base);
  float4 b = *(const float4*)(p1 + base);
  float4 c = *(const float4*)(p2 + base);
  float4 d = *(const float4*)(p3 + base);
  float4 x = *(const float4*)(X + base);
  float v[4];
  v[0] = x.x + a.x + b.x + c.x + d.x;
  v[1] = x.y + a.y + b.y + c.y + d.y;
  v[2] = x.z + a.z + b.z + c.z + d.z;
  v[3] = x.w + a.w + b.w + c.w + d.w;
  float ss = v[0]*v[0] + v[1]*v[1] + v[2]*v[2] + v[3]*v[3];
  __shared__ float red[256];
  red[tid] = ss; __syncthreads();
  for (int s = 128; s > 0; s >>= 1) { if (tid < s) red[tid] += red[tid+s]; __syncthreads(); }
  float scale = rsqrtf(red[0]/(float)DM + 1e-6f);
  float4 res; res.x = v[0]; res.y = v[1]; res.z = v[2]; res.w = v[3];
  *(float4*)(X + base) = res;
  bf16* Hr = H + (size_t)row*DM + tid*4;
  #pragma unroll
  for (int i = 0; i < 4; ++i) Hr[i] = f2b(v[i]*scale);
}

// ---- fused cproj-reduce + rmsnorm + token-shift, RACE-FREE form -------------
// Xnew = X + p0 + p1 computed on the fly for rows t and t-1 (X/p0/p1 are
// READ-ONLY -> no inter-block ordering dependence; round-6's race came from
// writing X in-place). Xnew is written to a DISTINCT buffer (the kernel's
// `out` tensor, unused until the final residual, which updates it in place).
__global__ void k_red2_rms_shift(const float* __restrict__ p0, const float* __restrict__ p1,
                                 const float* __restrict__ X, const float* __restrict__ maak,
                                 const float* __restrict__ maar, float* __restrict__ Xn,
                                 bf16* __restrict__ XK, bf16* __restrict__ XR) {
  int row = blockIdx.x; int t = row & (TT - 1);
  int tid = threadIdx.x;
  size_t base = (size_t)row*DM + tid*4;
  float4 a = *(const float4*)(p0 + base);
  float4 b = *(const float4*)(p1 + base);
  float4 x = *(const float4*)(X + base);
  float v[4], pv[4];
  v[0] = x.x + a.x + b.x; v[1] = x.y + a.y + b.y;
  v[2] = x.z + a.z + b.z; v[3] = x.w + a.w + b.w;
  if (t > 0) {
    float4 ap = *(const float4*)(p0 + base - DM);
    float4 bp = *(const float4*)(p1 + base - DM);
    float4 xp = *(const float4*)(X + base - DM);
    pv[0] = xp.x + ap.x + bp.x; pv[1] = xp.y + ap.y + bp.y;
    pv[2] = xp.z + ap.z + bp.z; pv[3] = xp.w + ap.w + bp.w;
  } else {
    pv[0] = pv[1] = pv[2] = pv[3] = 0.f;
  }
  float ss  = v[0]*v[0] + v[1]*v[1] + v[2]*v[2] + v[3]*v[3];
  float ssp = pv[0]*pv[0] + pv[1]*pv[1] + pv[2]*pv[2] + pv[3]*pv[3];
  __shared__ float red[256], red2[256];
  red[tid] = ss; red2[tid] = ssp; __syncthreads();
  for (int s = 128; s > 0; s >>= 1) {
    if (tid < s) { red[tid] += red[tid+s]; red2[tid] += red2[tid+s]; }
    __syncthreads();
  }
  float scale  = rsqrtf(red[0]/(float)DM + 1e-6f);
  float scalep = (t > 0) ? rsqrtf(red2[0]/(float)DM + 1e-6f) : 0.f;
  float4 res; res.x = v[0]; res.y = v[1]; res.z = v[2]; res.w = v[3];
  *(float4*)(Xn + base) = res;
  bf16* xk = XK + (size_t)row*DM; bf16* xrw = XR + (size_t)row*DM;
  #pragma unroll
  for (int i = 0; i < 4; ++i) {
    int c = tid*4 + i;
    float h = v[i]*scale;
    float xx = pv[i]*scalep - h;
    xk[c]  = f2b(h + xx*maak[c]);
    xrw[c] = f2b(h + xx*maar[c]);
  }
}

// ---------------- weight cast + transpose: Wt[n][k] = bf16(W[k][n]) ----------
__global__ void k_tcast(const float* __restrict__ W, bf16* __restrict__ Wt,
                        int K, int N) {
  __shared__ float t[32][33];
  int tx = threadIdx.x, ty = threadIdx.y;
  int n0 = blockIdx.x*32, k0 = blockIdx.y*32;
  #pragma unroll
  for (int i = 0; i < 4; ++i) {
    int k = k0 + ty + i*8, n = n0 + tx;
    t[ty + i*8][tx] = (n < N) ? W[(size_t)k*N + n] : 0.f;
  }
  __syncthreads();
  #pragma unroll
  for (int i = 0; i < 4; ++i) {
    int n = n0 + ty + i*8, k = k0 + tx;
    Wt[(size_t)n*K + k] = f2b(t[tx][ty + i*8]);
  }
}

// ---------------- MFMA GEMM 128x128, BK=32, 2-phase pipelined, 8 waves -------
// (BK=64 tried in round 10: +23us regression -- ds_read bytes/barrier doubled
// against the LDS 128B/clk throughput floor. BK=32 is the proven form.)
template<int EPI, bool ADD, bool OUTBF>
__global__ __launch_bounds__(512)
void mfma_gemm(const bf16* __restrict__ A, const bf16* __restrict__ Bt,
               float* __restrict__ C, bf16* __restrict__ Cbf,
               int M, int N, int K) {
  __shared__ bf16 As[2][128*32];
  __shared__ bf16 Bs[2][128*32];
  int tid = threadIdx.x;
  int wave = tid >> 6, lane = tid & 63;
  int m_l = lane & 15, quad = lane >> 4;
  int wr = (wave & 1) * 64, wc = (wave >> 1) * 32;
  int row0 = blockIdx.y * 128, col0 = blockIdx.x * 128;
  f32x4 acc[4][2];
  #pragma unroll
  for (int i = 0; i < 4; ++i)
    #pragma unroll
    for (int j = 0; j < 2; ++j) acc[i][j] = (f32x4){0.f,0.f,0.f,0.f};
  int lr = lane >> 2;            // 0..15 row within 16-row slab
  int lc = (lane & 3) * 8;       // 0,8,16,24
  int rbase = 16*wave;
  // prologue: stage tile 0
  gload16(&A [(size_t)(row0 + rbase + lr)*K + lc], &As[0][rbase*32]);
  gload16(&Bt[(size_t)(col0 + rbase + lr)*K + lc], &Bs[0][rbase*32]);
  __syncthreads();
  int nit = K >> 5;
  int cur = 0;
  for (int it = 0; it < nit; ++it) {
    if (it + 1 < nit) {
      int kn = (it + 1) << 5;
      gload16(&A [(size_t)(row0 + rbase + lr)*K + kn + lc], &As[cur^1][rbase*32]);
      gload16(&Bt[(size_t)(col0 + rbase + lr)*K + kn + lc], &Bs[cur^1][rbase*32]);
    }
    bf16x8 af[4], bfv[2];
    #pragma unroll
    for (int i = 0; i < 4; ++i) af[i]  = *(const bf16x8*)&As[cur][(wr + i*16 + m_l)*32 + quad*8];
    #pragma unroll
    for (int j = 0; j < 2; ++j) bfv[j] = *(const bf16x8*)&Bs[cur][(wc + j*16 + m_l)*32 + quad*8];
    #pragma unroll
    for (int i = 0; i < 4; ++i)
      #pragma unroll
      for (int j = 0; j < 2; ++j)
        acc[i][j] = __builtin_amdgcn_mfma_f32_16x16x32_bf16(af[i], bfv[j], acc[i][j], 0, 0, 0);
    __syncthreads();   // drains the prefetch (implicit vmcnt(0)) + syncs
    cur ^= 1;
  }
  #pragma unroll
  for (int i = 0; i < 4; ++i) {
    #pragma unroll
    for (int j = 0; j < 2; ++j) {
      int col = col0 + wc + j*16 + m_l;
      if (col < N) {
        #pragma unroll
        for (int r = 0; r < 4; ++r) {
          int row = row0 + wr + i*16 + quad*4 + r;
          float v = acc[i][j][r];
          if (EPI == 1) { v = fmaxf(v, 0.f); v = v*v; }          // relu^2
          else if (EPI == 2) v = 1.f/(1.f + __expf(-v));          // sigmoid
          if (OUTBF)      Cbf[(size_t)row*N + col] = f2b(v);
          else if (ADD)   C[(size_t)row*N + col] += v;
          else            C[(size_t)row*N + col]  = v;
        }
      }
    }
  }
}

// ---------------- split-K GEMM, BK=32, 2-phase pipelined, 8 waves ------------
__global__ __launch_bounds__(512)
void mfma_sk32(const bf16* __restrict__ A, const bf16* __restrict__ Bt,
               float* __restrict__ P0, float* __restrict__ P1,
               float* __restrict__ P2, float* __restrict__ P3,
               int M, int N, int K, int kchunk) {
  __shared__ bf16 As[2][128*32];
  __shared__ bf16 Bs[2][128*32];
  int tid = threadIdx.x;
  int wave = tid >> 6, lane = tid & 63;
  int m_l = lane & 15, quad = lane >> 4;
  int wr = (wave & 1) * 64, wc = (wave >> 1) * 32;
  int row0 = blockIdx.y * 128, col0 = blockIdx.x * 128;
  int kbeg = blockIdx.z * kchunk;
  f32x4 acc[4][2];
  #pragma unroll
  for (int i = 0; i < 4; ++i)
    #pragma unroll
    for (int j = 0; j < 2; ++j) acc[i][j] = (f32x4){0.f,0.f,0.f,0.f};
  int lr = lane >> 2;            // 0..15
  int lc = (lane & 3) * 8;       // 0,8,16,24
  int rbase = 16*wave;
  // prologue: stage tile kbeg
  gload16(&A [(size_t)(row0 + rbase + lr)*K + kbeg + lc], &As[0][rbase*32]);
  gload16(&Bt[(size_t)(col0 + rbase + lr)*K + kbeg + lc], &Bs[0][rbase*32]);
  __syncthreads();
  int nit = kchunk >> 5;
  int cur = 0;
  for (int it = 0; it < nit; ++it) {
    if (it + 1 < nit) {
      int kn = kbeg + ((it + 1) << 5);
      gload16(&A [(size_t)(row0 + rbase + lr)*K + kn + lc], &As[cur^1][rbase*32]);
      gload16(&Bt[(size_t)(col0 + rbase + lr)*K + kn + lc], &Bs[cur^1][rbase*32]);
    }
    bf16x8 af[4], bfv[2];
    #pragma unroll
    for (int i = 0; i < 4; ++i) af[i]  = *(const bf16x8*)&As[cur][(wr + i*16 + m_l)*32 + quad*8];
    #pragma unroll
    for (int j = 0; j < 2; ++j) bfv[j] = *(const bf16x8*)&Bs[cur][(wc + j*16 + m_l)*32 + quad*8];
    #pragma unroll
    for (int i = 0; i < 4; ++i)
      #pragma unroll
      for (int j = 0; j < 2; ++j)
        acc[i][j] = __builtin_amdgcn_mfma_f32_16x16x32_bf16(af[i], bfv[j], acc[i][j], 0, 0, 0);
    __syncthreads();
    cur ^= 1;
  }
  float* P = (blockIdx.z == 0) ? P0 : (blockIdx.z == 1) ? P1 : (blockIdx.z == 2) ? P2 : P3;
  #pragma unroll
  for (int i = 0; i < 4; ++i) {
    #pragma unroll
    for (int j = 0; j < 2; ++j) {
      int col = col0 + wc + j*16 + m_l;
      if (col < N) {
        #pragma unroll
        for (int r = 0; r < 4; ++r) {
          int row = row0 + wr + i*16 + quad*4 + r;
          P[(size_t)row*N + col] = acc[i][j][r];
        }
      }
    }
  }
}

// -------- fused final: xio = xio + sigmoid(r0+r1) * (k0+k1+k2+k3) ------------
// xio is read-modify-write in place (same element per thread -> safe).
__global__ void k_reduce_final7(const float* __restrict__ k0, const float* __restrict__ k1,
                                const float* __restrict__ k2, const float* __restrict__ k3,
                                const float* __restrict__ r0p, const float* __restrict__ r1p,
                                float* __restrict__ xio) {
  size_t i = ((size_t)blockIdx.x*256 + threadIdx.x)*4;
  float4 a = *(const float4*)(k0 + i);
  float4 b = *(const float4*)(k1 + i);
  float4 c = *(const float4*)(k2 + i);
  float4 d = *(const float4*)(k3 + i);
  float4 ra = *(const float4*)(r0p + i);
  float4 rb = *(const float4*)(r1p + i);
  float4 x = *(const float4*)(xio + i);
  float kvx = a.x + b.x + c.x + d.x, kvy = a.y + b.y + c.y + d.y;
  float kvz = a.z + b.z + c.z + d.z, kvw = a.w + b.w + c.w + d.w;
  float sx = 1.f/(1.f + __expf(-(ra.x + rb.x)));
  float sy = 1.f/(1.f + __expf(-(ra.y + rb.y)));
  float sz = 1.f/(1.f + __expf(-(ra.z + rb.z)));
  float sw = 1.f/(1.f + __expf(-(ra.w + rb.w)));
  float4 res;
  res.x = x.x + sx*kvx; res.y = x.y + sy*kvy;
  res.z = x.z + sz*kvz; res.w = x.w + sw*kvw;
  *(float4*)(xio + i) = res;
}

// ---------------- SSM conv (K=4) + silu + dt softplus; bf16 xBC out ----------
__global__ void k_conv_ssm(const float* __restrict__ ZXr, const float* __restrict__ cw,
                           const float* __restrict__ cb, const float* __restrict__ dtb,
                           bf16* __restrict__ XBCb, float* __restrict__ DT) {
  int bt = blockIdx.x; int b = bt >> 10; int t = bt & 1023;
  int tid = threadIdx.x;
  for (int c = tid; c < NXBC; c += 256) {
    float acc = cb[c];
    #pragma unroll
    for (int kk = 0; kk < 4; ++kk) {
      int ts = t - 3 + kk;
      if (ts >= 0) acc += cw[c*4+kk] * ZXr[((size_t)(b*TT+ts))*NXBCD + c];
    }
    float s = acc / (1.f + __expf(-acc));  // silu
    XBCb[(size_t)bt*NXBC + c] = f2b(s);
  }
  if (tid < NHS) {
    float x = ZXr[(size_t)bt*NXBCD + NXBC + tid] + dtb[tid];
    float sp = (x > 20.f) ? x : log1pf(__expf(x));
    DT[(size_t)bt*NHS + tid] = sp;
  }
}

// ---------------- scan pass 1: intra-chunk via MFMA, 8 waves -----------------
__global__ __launch_bounds__(512)
void k_scan1(const bf16* __restrict__ xbcb, const float* __restrict__ dt,
             const float* __restrict__ A_log, const float* __restrict__ Dmv,
             float* __restrict__ Y, float* __restrict__ SC, float* __restrict__ CUM) {
  int bc = blockIdx.x;
  int bh = bc >> 3, c = bc & 7;
  int b = bh >> 5, h = bh & 31;
  int tid = threadIdx.x, wave = tid >> 6, lane = tid & 63;
  int col = lane & 15, quad = lane >> 4;
  int t0 = c * CL;
  __shared__ bf16 sB[128*136];   // B rows [s][n]; later BwT [n][s]
  __shared__ bf16 sC[128*136];   // C rows [t][n]; later Ps [t][s]
  __shared__ bf16 sxT[64*136];   // x^T [p][t]
  __shared__ float sL[128], sdt[128], sW[128];
  float A = -__expf(A_log[h]);
  float Dmh = Dmv[h];
  for (int e = tid; e < 128*16; e += 512) {
    int r = e >> 4, ch = e & 15;
    const bf16* row = xbcb + (size_t)(b*TT + t0 + r)*NXBC;
    *(uint4*)&sB[r*136 + ch*8] = *(const uint4*)&row[2048 + ch*8];
    *(uint4*)&sC[r*136 + ch*8] = *(const uint4*)&row[2176 + ch*8];
  }
  for (int e = tid; e < 64*128; e += 512) {
    int p = e & 63, t = e >> 6;
    sxT[p*136 + t] = xbcb[(size_t)(b*TT + t0 + t)*NXBC + h*64 + p];
  }
  if (tid < 128) sdt[tid] = dt[(size_t)(b*TT + t0 + tid)*NHS + h];
  __syncthreads();
  if (wave == 0) {
    float a0 = sdt[2*lane]*A, a1 = sdt[2*lane+1]*A;
    float tot = a0 + a1;
    #pragma unroll
    for (int off = 1; off < 64; off <<= 1) {
      float up = __shfl_up(tot, off);
      if (lane >= off) tot += up;
    }
    sL[2*lane+1] = tot;
    sL[2*lane]   = tot - a1;
  }
  __syncthreads();
  // MFMA1: g[t][s] = C @ B^T; wave tiling 2 (t-halves) x 4 (s-quarters)
  int wr = (wave & 1)*64, wc = (wave >> 1)*32;
  f32x4 g[4][2];
  #pragma unroll
  for (int i = 0; i < 4; ++i)
    #pragma unroll
    for (int j = 0; j < 2; ++j) g[i][j] = (f32x4){0.f,0.f,0.f,0.f};
  #pragma unroll
  for (int kf = 0; kf < 4; ++kf) {
    bf16x8 af[4], bfr[2];
    #pragma unroll
    for (int i = 0; i < 4; ++i) af[i]  = *(const bf16x8*)&sC[(wr + i*16 + col)*136 + kf*32 + quad*8];
    #pragma unroll
    for (int j = 0; j < 2; ++j) bfr[j] = *(const bf16x8*)&sB[(wc + j*16 + col)*136 + kf*32 + quad*8];
    #pragma unroll
    for (int i = 0; i < 4; ++i)
      #pragma unroll
      for (int j = 0; j < 2; ++j)
        g[i][j] = __builtin_amdgcn_mfma_f32_16x16x32_bf16(af[i], bfr[j], g[i][j], 0, 0, 0);
  }
  float Lend = sL[127];
  if (tid < 128) sW[tid] = __expf(Lend - sL[tid]) * sdt[tid];
  __syncthreads();
  if (tid < 128) CUM[(size_t)bh*TT + t0 + tid] = __expf(sL[tid]);
  #pragma unroll
  for (int i = 0; i < 4; ++i) {
    #pragma unroll
    for (int j = 0; j < 2; ++j) {
      int sl = wc + j*16 + col;
      #pragma unroll
      for (int r = 0; r < 4; ++r) {
        int tl = wr + i*16 + quad*4 + r;
        float v = (sl <= tl) ? g[i][j][r] * __expf(sL[tl] - sL[sl]) * sdt[sl] : 0.f;
        sC[tl*136 + sl] = f2b(v);
      }
    }
  }
  for (int e = tid; e < 128*128; e += 512) {
    int n = e & 127, s = e >> 7;
    sB[n*136 + s] = f2b(b2f(xbcb[(size_t)(b*TT + t0 + s)*NXBC + 2048 + n]) * sW[s]);
  }
  __syncthreads();
  // MFMA2: y[t][p] = Ps @ x^T^T; wave tiling 4 (t-quarters) x 2 (p-halves)
  int tb = (wave & 3)*32, pb = (wave >> 2)*32;
  f32x4 ya[2][2];
  #pragma unroll
  for (int i2 = 0; i2 < 2; ++i2)
    #pragma unroll
    for (int jd = 0; jd < 2; ++jd) ya[i2][jd] = (f32x4){0.f,0.f,0.f,0.f};
  #pragma unroll
  for (int kf = 0; kf < 4; ++kf) {
    bf16x8 pa[2], xa[2];
    #pragma unroll
    for (int i2 = 0; i2 < 2; ++i2)
      pa[i2] = *(const bf16x8*)&sC[(tb + i2*16 + col)*136 + kf*32 + quad*8];
    #pragma unroll
    for (int jd = 0; jd < 2; ++jd)
      xa[jd] = *(const bf16x8*)&sxT[(pb + jd*16 + col)*136 + kf*32 + quad*8];
    #pragma unroll
    for (int i2 = 0; i2 < 2; ++i2)
      #pragma unroll
      for (int jd = 0; jd < 2; ++jd)
        ya[i2][jd] = __builtin_amdgcn_mfma_f32_16x16x32_bf16(pa[i2], xa[jd], ya[i2][jd], 0, 0, 0);
  }
  #pragma unroll
  for (int i2 = 0; i2 < 2; ++i2) {
    #pragma unroll
    for (int jd = 0; jd < 2; ++jd) {
      int p = pb + jd*16 + col;
      #pragma unroll
      for (int r = 0; r < 4; ++r) {
        int tl = tb + i2*16 + quad*4 + r;
        float xv = b2f(sxT[p*136 + tl]);
        Y[(size_t)(b*TT + t0 + tl)*DI + h*64 + p] = ya[i2][jd][r] + xv*Dmh;
      }
    }
  }
  // MFMA3: SC[p][n] = x^T @ Bw^T; wave tiling 4 (p-16-blocks) x 2 (n-halves)
  int pb3 = (wave & 3)*16, nb = (wave >> 2)*64;
  f32x4 sa[4];
  #pragma unroll
  for (int nt = 0; nt < 4; ++nt) sa[nt] = (f32x4){0.f,0.f,0.f,0.f};
  #pragma unroll
  for (int kf = 0; kf < 4; ++kf) {
    bf16x8 xpa = *(const bf16x8*)&sxT[(pb3 + col)*136 + kf*32 + quad*8];
    #pragma unroll
    for (int nt = 0; nt < 4; ++nt) {
      bf16x8 bwa = *(const bf16x8*)&sB[(nb + nt*16 + col)*136 + kf*32 + quad*8];
      sa[nt] = __builtin_amdgcn_mfma_f32_16x16x32_bf16(xpa, bwa, sa[nt], 0, 0, 0);
    }
  }
  #pragma unroll
  for (int nt = 0; nt < 4; ++nt) {
    int n = nb + nt*16 + col;
    #pragma unroll
    for (int r = 0; r < 4; ++r) {
      int p = pb3 + quad*4 + r;
      SC[((size_t)(bh*NC + c)*64 + p)*128 + n] = sa[nt][r];
    }
  }
}

// ---------------- scan pass 2: sequential inter-chunk combine (fp32) ---------
__global__ __launch_bounds__(512)
void k_scan2(float* __restrict__ SC, const float* __restrict__ CUM) {
  int bh = blockIdx.x;
  int tid = threadIdx.x;
  int p = tid >> 3, g = tid & 7;
  float S[16];
  #pragma unroll
  for (int j = 0; j < 16; ++j) S[j] = 0.f;
  for (int c = 0; c < NC; ++c) {
    size_t base = ((size_t)(bh*NC + c)*64 + p)*128 + g*16;
    float Ptot = CUM[(size_t)bh*TT + c*CL + (CL-1)];
    float tmp[16];
    #pragma unroll
    for (int j = 0; j < 16; ++j) tmp[j] = SC[base + j];
    #pragma unroll
    for (int j = 0; j < 16; ++j) SC[base + j] = S[j];
    #pragma unroll
    for (int j = 0; j < 16; ++j) S[j] = S[j]*Ptot + tmp[j];
  }
}

// ---------------- scan pass 3: Y += CUM[t] * (C @ S_init^T) via MFMA ---------
__global__ __launch_bounds__(256)
void k_scan3(const bf16* __restrict__ xbcb, const float* __restrict__ SC,
             const float* __restrict__ CUM, float* __restrict__ Y) {
  int bc = blockIdx.x;
  int bh = bc >> 3, c = bc & 7;
  if (c == 0) return;
  int b = bh >> 5, h = bh & 31;
  int tid = threadIdx.x, wave = tid >> 6, lane = tid & 63;
  int col = lane & 15, quad = lane >> 4;
  int t0 = c * CL;
  __shared__ bf16 sCt[128*136];
  __shared__ bf16 sS[64*136];
  __shared__ float sCum[128];
  for (int e = tid; e < 128*16; e += 256) {
    int r = e >> 4, ch = e & 15;
    *(uint4*)&sCt[r*136 + ch*8] =
      *(const uint4*)&xbcb[(size_t)(b*TT + t0 + r)*NXBC + 2176 + ch*8];
  }
  for (int e = tid; e < 64*128; e += 256) {
    int n = e & 127, p = e >> 7;
    sS[p*136 + n] = f2b(SC[((size_t)(bh*NC + c)*64 + p)*128 + n]);
  }
  if (tid < 128) sCum[tid] = CUM[(size_t)bh*TT + t0 + tid];
  __syncthreads();
  f32x4 ya[2][4];
  #pragma unroll
  for (int i2 = 0; i2 < 2; ++i2)
    #pragma unroll
    for (int jd = 0; jd < 4; ++jd) ya[i2][jd] = (f32x4){0.f,0.f,0.f,0.f};
  #pragma unroll
  for (int kf = 0; kf < 4; ++kf) {
    bf16x8 pa[2], sv[4];
    #pragma unroll
    for (int i2 = 0; i2 < 2; ++i2)
      pa[i2] = *(const bf16x8*)&sCt[(wave*32 + i2*16 + col)*136 + kf*32 + quad*8];
    #pragma unroll
    for (int jd = 0; jd < 4; ++jd)
      sv[jd] = *(const bf16x8*)&sS[(jd*16 + col)*136 + kf*32 + quad*8];
    #pragma unroll
    for (int i2 = 0; i2 < 2; ++i2)
      #pragma unroll
      for (int jd = 0; jd < 4; ++jd)
        ya[i2][jd] = __builtin_amdgcn_mfma_f32_16x16x32_bf16(pa[i2], sv[jd], ya[i2][jd], 0, 0, 0);
  }
  #pragma unroll
  for (int i2 = 0; i2 < 2; ++i2) {
    #pragma unroll
    for (int jd = 0; jd < 4; ++jd) {
      int p = jd*16 + col;
      #pragma unroll
      for (int r = 0; r < 4; ++r) {
        int tl = wave*32 + i2*16 + quad*4 + r;
        Y[(size_t)(b*TT + t0 + tl)*DI + h*64 + p] += sCum[tl]*ya[i2][jd][r];
      }
    }
  }
}

// ---------------- gate: Ybf = bf16(rmsnorm(y * silu(z)) * mnorm_w) -----------
__global__ void k_gate(const float* __restrict__ Y, const float* __restrict__ Z,
                       const float* __restrict__ mnw, bf16* __restrict__ Ybf) {
  int row = blockIdx.x; int tid = threadIdx.x;
  const float* yr = Y + (size_t)row*DI;
  const float* zr = Z + (size_t)row*DI;
  float gv[8]; float ss = 0.f;
  #pragma unroll
  for (int i = 0; i < 8; ++i) {
    int c = tid*8 + i;
    float z = zr[c];
    float sz = z / (1.f + __expf(-z));
    float v = yr[c]*sz;
    gv[i] = v; ss += v*v;
  }
  __shared__ float red[256];
  red[tid] = ss; __syncthreads();
  for (int s = 128; s > 0; s >>= 1) { if (tid < s) red[tid] += red[tid+s]; __syncthreads(); }
  float scale = rsqrtf(red[0]/(float)DI + 1e-5f);
  bf16* br = Ybf + (size_t)row*DI;
  #pragma unroll
  for (int i = 0; i < 8; ++i) { int c = tid*8 + i; br[c] = f2b(gv[i]*scale*mnw[c]); }
}

// ------ q/k/v causal dwconv (K=3) with FUSED split-K reduce of QKV -----------
__global__ void k_conv_qkv(const float* __restrict__ P0, const float* __restrict__ P1,
                           const float* qw, const float* qb, const float* kw, const float* kb,
                           const float* vw, const float* vb,
                           bf16* __restrict__ Qb, bf16* __restrict__ Kb, bf16* __restrict__ Vtb) {
  int bt = blockIdx.x; int b = bt >> 10; int t = bt & 1023;
  int tid = threadIdx.x;
  for (int c = tid; c < 1152; c += 256) {
    if (c < 1024) {
      int h = c >> 6, d = c & 63;
      float acc = qb[d];
      #pragma unroll
      for (int kk = 0; kk < 3; ++kk) {
        int ts = t-2+kk;
        if (ts >= 0) { size_t ix = ((size_t)(b*TT+ts))*1152 + c; acc += qw[d*3+kk] * (P0[ix] + P1[ix]); }
      }
      Qb[((size_t)(b*NHA + h)*TT + t)*HD + d] = f2b(acc * 0.125f);  // 1/sqrt(64)
    } else if (c < 1088) {
      int d = c - 1024;
      float acc = kb[d];
      #pragma unroll
      for (int kk = 0; kk < 3; ++kk) {
        int ts = t-2+kk;
        if (ts >= 0) { size_t ix = ((size_t)(b*TT+ts))*1152 + c; acc += kw[d*3+kk] * (P0[ix] + P1[ix]); }
      }
      Kb[(size_t)bt*HD + d] = f2b(acc);
    } else {
      int d = c - 1088;
      float acc = vb[d];
      #pragma unroll
      for (int kk = 0; kk < 3; ++kk) {
        int ts = t-2+kk;
        if (ts >= 0) { size_t ix = ((size_t)(b*TT+ts))*1152 + c; acc += vw[d*3+kk] * (P0[ix] + P1[ix]); }
      }
      Vtb[((size_t)(b*HD + d))*TT + t] = f2b(acc);
    }
  }
}

// ---------------- split-KV MFMA flash attention, max-free, 8 waves -----------
__global__ __launch_bounds__(512)
void k_flash_sk(const bf16* __restrict__ Qb, const bf16* __restrict__ Kb,
                const bf16* __restrict__ Vtb, float* __restrict__ Op,
                float* __restrict__ Lp) {
  int qt = blockIdx.x >> 1, z = blockIdx.x & 1;
  int h = blockIdx.y, b = blockIdx.z;
  int n = qt + 1;
  int kmid = (n + 1) >> 1;
  int kbeg = z ? kmid : 0;
  int kend = z ? n : kmid;
  int tid = threadIdx.x, wave = tid >> 6, lane = tid & 63;
  int col = lane & 15, quad = lane >> 4;
  int t0 = qt * 128;
  __shared__ bf16 Ks[128*72];
  __shared__ bf16 Vs[64*136];
  __shared__ bf16 Ps[8][16*136];
  const bf16* Qbase = Qb + ((size_t)(b*NHA + h))*TT*HD;
  float lst[4];
  f32x4 oacc[4];
  #pragma unroll
  for (int r = 0; r < 4; ++r) lst[r] = 0.f;
  #pragma unroll
  for (int jd = 0; jd < 4; ++jd) oacc[jd] = (f32x4){0.f,0.f,0.f,0.f};
  if (kbeg < kend) {
    bf16x8 qf[2];
    #pragma unroll
    for (int kf = 0; kf < 2; ++kf)
      qf[kf] = *(const bf16x8*)&Qbase[(size_t)(t0 + wave*16 + col)*HD + kf*32 + quad*8];

    for (int kt = kbeg; kt < kend; ++kt) {
      int s0 = kt * 128;
      __syncthreads();
      for (int e = tid; e < 1024; e += 512) {
        int r = e >> 3, ch = e & 7;
        *(uint4*)&Ks[r*72 + ch*8] = *(const uint4*)&Kb[((size_t)(b*TT + s0 + r))*HD + ch*8];
      }
      for (int e = tid; e < 1024; e += 512) {
        int d = e >> 4, ch = e & 15;
        *(uint4*)&Vs[d*136 + ch*8] = *(const uint4*)&Vtb[((size_t)(b*HD + d))*TT + s0 + ch*8];
      }
      __syncthreads();
      f32x4 sacc[8];
      #pragma unroll
      for (int j = 0; j < 8; ++j) sacc[j] = (f32x4){0.f,0.f,0.f,0.f};
      __builtin_amdgcn_s_setprio(1);
      #pragma unroll
      for (int j = 0; j < 8; ++j) {
        bf16x8 kf0 = *(const bf16x8*)&Ks[(j*16 + col)*72 + quad*8];
        bf16x8 kf1 = *(const bf16x8*)&Ks[(j*16 + col)*72 + 32 + quad*8];
        sacc[j] = __builtin_amdgcn_mfma_f32_16x16x32_bf16(qf[0], kf0, sacc[j], 0, 0, 0);
        sacc[j] = __builtin_amdgcn_mfma_f32_16x16x32_bf16(qf[1], kf1, sacc[j], 0, 0, 0);
      }
      __builtin_amdgcn_s_setprio(0);
      bool diag = (kt == qt);
      #pragma unroll
      for (int r = 0; r < 4; ++r) {
        int rowloc = wave*16 + quad*4 + r;
        #pragma unroll
        for (int j = 0; j < 8; ++j) {
          float pv = __expf(sacc[j][r]);
          if (diag && (j*16 + col > rowloc)) pv = 0.f;
          sacc[j][r] = pv;
          lst[r] += pv;
        }
      }
      #pragma unroll
      for (int j = 0; j < 8; ++j)
        #pragma unroll
        for (int r = 0; r < 4; ++r)
          Ps[wave][(quad*4 + r)*136 + j*16 + col] = f2b(sacc[j][r]);
      __builtin_amdgcn_s_setprio(1);
      bf16x8 pa[4];
      #pragma unroll
      for (int kf = 0; kf < 4; ++kf)
        pa[kf] = *(const bf16x8*)&Ps[wave][col*136 + kf*32 + quad*8];
      #pragma unroll
      for (int jd = 0; jd < 4; ++jd) {
        #pragma unroll
        for (int kf = 0; kf < 4; ++kf) {
          bf16x8 vbf = *(const bf16x8*)&Vs[(jd*16 + col)*136 + kf*32 + quad*8];
          oacc[jd] = __builtin_amdgcn_mfma_f32_16x16x32_bf16(pa[kf], vbf, oacc[jd], 0, 0, 0);
        }
      }
      __builtin_amdgcn_s_setprio(0);
    }
    #pragma unroll
    for (int r = 0; r < 4; ++r) {
      float l = lst[r];
      l += __shfl_xor(l, 1);
      l += __shfl_xor(l, 2);
      l += __shfl_xor(l, 4);
      l += __shfl_xor(l, 8);
      lst[r] = l;
    }
  }
  if (qt == 0 && z == 1) return;
  size_t robase = ((size_t)((z*BB + b)*NHA + h))*TT + t0;
  #pragma unroll
  for (int jd = 0; jd < 4; ++jd) {
    int d = jd*16 + col;
    #pragma unroll
    for (int r = 0; r < 4; ++r) {
      int tl = wave*16 + quad*4 + r;
      Op[(robase + tl)*HD + d] = oacc[jd][r];
    }
  }
  if (col == 0) {
    #pragma unroll
    for (int r = 0; r < 4; ++r) {
      int tl = wave*16 + quad*4 + r;
      Lp[robase + tl] = lst[r];
    }
  }
}

// ---------------- attention split-KV combine (max-free: pure sums) -----------
__global__ void k_att_comb(const float* __restrict__ Op, const float* __restrict__ Lp,
                           bf16* __restrict__ outb) {
  int idx = blockIdx.x*256 + threadIdx.x;   // one thread = 4 consecutive d
  int e = idx*4;
  int c = e & (DM - 1); int h = c >> 6; int d = c & 63;
  int bt = e >> 10; int t = bt & (TT - 1); int b = bt >> 10;
  int qt = t >> 7;
  size_t r0 = ((size_t)(b*NHA + h))*TT + t;
  float4 o0 = *(const float4*)&Op[r0*HD + d];
  float l = Lp[r0];
  float ox = o0.x, oy = o0.y, oz = o0.z, ow = o0.w;
  if (qt > 0) {
    size_t r1 = ((size_t)((BB + b)*NHA + h))*TT + t;
    float4 o1 = *(const float4*)&Op[r1*HD + d];
    l += Lp[r1];
    ox += o1.x; oy += o1.y; oz += o1.z; ow += o1.w;
  }
  float inv = 1.f / l;
  bf16* p = outb + (size_t)bt*DM + c;
  p[0] = f2b(ox*inv); p[1] = f2b(oy*inv); p[2] = f2b(oz*inv); p[3] = f2b(ow*inv);
}

// =============================================================================
extern "C" void kernel_launch(void* const* d_in, const int* in_sizes, int n_in,
                              void* d_out, int out_size, void* d_ws, size_t ws_size,
                              hipStream_t stream) {
  const float* x_in    = (const float*)d_in[0];
  const float* W_in    = (const float*)d_in[1];
  const float* conv_w  = (const float*)d_in[2];
  const float* conv_b  = (const float*)d_in[3];
  const float* A_log   = (const float*)d_in[4];
  const float* Dm      = (const float*)d_in[5];
  const float* dt_bias = (const float*)d_in[6];
  const float* mnorm_w = (const float*)d_in[7];
  const float* W_out   = (const float*)d_in[8];
  const float* W_qkv   = (const float*)d_in[9];
  const float* W_cproj = (const float*)d_in[10];
  const float* qconv_w = (const float*)d_in[11];
  const float* qconv_b = (const float*)d_in[12];
  const float* kconv_w = (const float*)d_in[13];
  const float* kconv_b = (const float*)d_in[14];
  const float* vconv_w = (const float*)d_in[15];
  const float* vconv_b = (const float*)d_in[16];
  const float* maa_k   = (const float*)d_in[17];
  const float* maa_r   = (const float*)d_in[18];
  const float* W_key   = (const float*)d_in[19];
  const float* W_rec   = (const float*)d_in[20];
  const float* W_val   = (const float*)d_in[21];
  float* out = (float*)d_out;

  float* ws = (float*)d_ws;
  float* X       = ws;                       // [0, 2,097,152)
  bf16*  Hbf     = (bf16*)(ws + 2097152);    // 2,097,152 bf16
  float* Zbuf    = ws + 3145728;             // [3,145,728, 7,340,032)
  float* XBCDraw = ws + 7340032;             // [7,340,032, 12,124,160)
  float* XBC     = ws + 12124160;            // [12,124,160, 16,842,752)
  float* DT      = ws + 16842752;            // +65,536
  float* CUM     = ws + 16908288;            // +65,536
  float* Y       = ws + 16973824;            // [16,973,824, 21,168,128)

  bf16*  Wt_in    = (bf16*)XBC;
  bf16*  XBCb     = (bf16*)XBC;
  float* SC       = XBCDraw;
  bf16*  Ybf      = (bf16*)XBC;
  bf16*  Wt_out   = (bf16*)(XBC + 2097152);
  bf16*  Wt_qkv   = (bf16*)XBC;
  bf16*  Qb       = (bf16*)XBCDraw;
  bf16*  Kb       = (bf16*)(XBCDraw + 1048576);
  bf16*  Vtb      = (bf16*)(XBCDraw + 1114112);
  bf16*  ATTNbf   = (bf16*)Y;
  bf16*  Wt_cproj = (bf16*)(Y + 1048576);
  bf16*  XKbf     = (bf16*)XBC;
  bf16*  XRbf     = (bf16*)(XBC + 1048576);
  bf16*  Wt_key   = (bf16*)Zbuf;
  bf16*  KFbf     = (bf16*)XBCDraw;
  bf16*  Wt_val   = (bf16*)Zbuf;
  bf16*  Wt_rec   = (bf16*)Zbuf;
  // flash split-KV partials (live only between k_conv_qkv and k_att_comb):
  float* FOp      = Zbuf;                    // 2 x 2,097,152 fp32
  float* FLp      = ws + 2097152;            // 65,536 (Hbf region, dead here)

  dim3 thr256(256), thr512(512);
  dim3 tblk(32, 8);

  // 1. X = x; Hbf = rmsnorm(x)
  k_rms_in<<<BT, thr256, 0, stream>>>(x_in, X, Hbf);
  // 2. [Z | XBCDraw] = Hbf @ W_in  (wide, full-K)
  k_tcast<<<dim3(4480/32, 1024/32), tblk, 0, stream>>>(W_in, Wt_in, 1024, NZX);
  mfma_gemm<0,false,false><<<dim3(16, 16), thr512, 0, stream>>>(Hbf, Wt_in, Zbuf, nullptr, BT, 2048, 1024);
  mfma_gemm<0,false,false><<<dim3(19, 16), thr512, 0, stream>>>(Hbf, Wt_in + (size_t)2048*1024, XBCDraw, nullptr, BT, NXBCD, 1024);
  // 3. conv+silu on xBC (bf16 out), softplus dt
  k_conv_ssm<<<BT, thr256, 0, stream>>>(XBCDraw, conv_w, conv_b, dt_bias, XBCb, DT);
  // 4. SSM chunked scan via MFMA (scan1 8 waves)
  k_scan1<<<BB*NHS*NC, thr512, 0, stream>>>(XBCb, DT, A_log, Dm, Y, SC, CUM);
  k_scan2<<<BB*NHS, thr512, 0, stream>>>(SC, CUM);
  k_scan3<<<BB*NHS*NC, thr256, 0, stream>>>(XBCb, SC, CUM, Y);
  // 5. gate + mnorm -> Ybf
  k_gate<<<BT, thr256, 0, stream>>>(Y, Zbuf, mnorm_w, Ybf);
  // 6+7. X += Ybf @ W_out (split-K z=4) -> fused reduce + rmsnorm -> Hbf
  k_tcast<<<dim3(1024/32, 2048/32), tblk, 0, stream>>>(W_out, Wt_out, 2048, 1024);
  mfma_sk32<<<dim3(8, 16, 4), thr512, 0, stream>>>(Ybf, Wt_out,
      Zbuf, Zbuf + 2097152, XBCDraw, XBCDraw + 2097152, BT, 1024, 2048, 512);
  k_reduce4_rms<<<BT, thr256, 0, stream>>>(Zbuf, Zbuf + 2097152, XBCDraw, XBCDraw + 2097152, X, Hbf);
  // 8. QKV partials = Hbf @ W_qkv (split-K z=2; p0 -> Zbuf, p1 -> Y;
  //    reduce FUSED into conv_qkv)
  k_tcast<<<dim3(1152/32, 1024/32), tblk, 0, stream>>>(W_qkv, Wt_qkv, 1024, 1152);
  mfma_sk32<<<dim3(9, 16, 2), thr512, 0, stream>>>(Hbf, Wt_qkv,
      Zbuf, Y, Zbuf, Zbuf, BT, 1152, 1024, 512);
  // 9. q/k/v convs (fused QKV reduce) -> bf16 Qb (scaled), Kb, Vtb (transposed)
  k_conv_qkv<<<BT, thr256, 0, stream>>>(Zbuf, Y, qconv_w, qconv_b, kconv_w, kconv_b, vconv_w, vconv_b, Qb, Kb, Vtb);
  // 10. split-KV max-free flash attention (8 waves) -> partials -> combine
  k_flash_sk<<<dim3((TT/128)*2, NHA, BB), thr512, 0, stream>>>(Qb, Kb, Vtb, FOp, FLp);
  k_att_comb<<<(BT*DM)/(256*4), thr256, 0, stream>>>(FOp, FLp, ATTNbf);
  // 11+12+13. cproj partials (split-K z=2 -> Zbuf) then RACE-FREE fused
  //   reduce + rmsnorm + token-shift: reads X/p0/p1 only, writes Xnew to `out`
  //   (distinct buffer, in-place-updated by the final kernel) + XKbf/XRbf.
  k_tcast<<<dim3(1024/32, 1024/32), tblk, 0, stream>>>(W_cproj, Wt_cproj, 1024, 1024);
  mfma_sk32<<<dim3(8, 16, 2), thr512, 0, stream>>>(ATTNbf, Wt_cproj,
      Zbuf, Zbuf + 2097152, Zbuf, Zbuf, BT, 1024, 1024, 512);
  k_red2_rms_shift<<<BT, thr256, 0, stream>>>(Zbuf, Zbuf + 2097152, X, maa_k, maa_r, out, XKbf, XRbf);
  // 14. KFbf = bf16(relu(XKbf @ W_key)^2)  (cproj partials dead -> Zbuf free)
  k_tcast<<<dim3(4096/32, 1024/32), tblk, 0, stream>>>(W_key, Wt_key, 1024, 4096);
  mfma_gemm<1,false,true><<<dim3(32, 16), thr512, 0, stream>>>(XKbf, Wt_key, nullptr, KFbf, BT, 4096, 1024);
  // 15. KV partials = KFbf @ W_val  (split-K z=4; NO reduce -- fused into final)
  k_tcast<<<dim3(1024/32, 4096/32), tblk, 0, stream>>>(W_val, Wt_val, 4096, 1024);
  mfma_sk32<<<dim3(8, 16, 4), thr512, 0, stream>>>(KFbf, Wt_val,
      Y, Y + 2097152, XBC + 2621440, Zbuf + 2097152, BT, 1024, 4096, 1024);
  // 16. R partials = XRbf @ W_rec (split-K z=2 -> XBCDraw; KFbf dead)
  k_tcast<<<dim3(1024/32, 1024/32), tblk, 0, stream>>>(W_rec, Wt_rec, 1024, 1024);
  mfma_sk32<<<dim3(8, 16, 2), thr512, 0, stream>>>(XRbf, Wt_rec,
      XBCDraw, XBCDraw + 2097152, XBCDraw, XBCDraw, BT, 1024, 1024, 512);
  // 17. fused final (in place on out): out += sigmoid(r0+r1) * (k0+k1+k2+k3)
  k_reduce_final7<<<2048, thr256, 0, stream>>>(
      Y, Y + 2097152, XBC + 2621440, Zbuf + 2097152,
      XBCDraw, XBCDraw + 2097152, out);
}